// Round 4
// baseline (953.971 us; speedup 1.0000x reference)
//
#include <hip/hip_runtime.h>
#include <hip/hip_bf16.h>
#include <hip/hip_fp16.h>

#define H_FEATS 128
#define HIDDEN  32
#define BUCKET_SHIFT 7            // 128 nodes per bucket = 32KB of fp16 rows
#define MAX_BUCKETS 1024

union H8 { uint4 u; __half2 h2[4]; };

// ---- Pass 1: h (fp32) -> fp16 rows in ws ----
__global__ __launch_bounds__(256) void convert_h_kernel(
    const float* __restrict__ h, __half* __restrict__ hh, int n8)
{
    int i = blockIdx.x * blockDim.x + threadIdx.x;
    if (i >= n8) return;
    const float4* s = reinterpret_cast<const float4*>(h) + (size_t)i * 2;
    float4 a = s[0], b = s[1];
    H8 r;
    r.h2[0] = __floats2half2_rn(a.x, a.y);
    r.h2[1] = __floats2half2_rn(a.z, a.w);
    r.h2[2] = __floats2half2_rn(b.x, b.y);
    r.h2[3] = __floats2half2_rn(b.z, b.w);
    reinterpret_cast<uint4*>(hh)[i] = r.u;
}

// ---- Counting sort by src bucket ----
__global__ __launch_bounds__(256) void zero_hist_kernel(int* __restrict__ hist, int n)
{
    int i = blockIdx.x * blockDim.x + threadIdx.x;
    if (i < n) hist[i] = 0;
}

__global__ __launch_bounds__(256) void hist_kernel(
    const int* __restrict__ src, int* __restrict__ hist, int n_edges)
{
    int e = blockIdx.x * blockDim.x + threadIdx.x;
    if (e >= n_edges) return;
    atomicAdd(&hist[src[e] >> BUCKET_SHIFT], 1);
}

// single-block exclusive scan (nbuck <= 1024) -> cursor
__global__ __launch_bounds__(MAX_BUCKETS) void scan_kernel(
    const int* __restrict__ hist, int* __restrict__ cursor, int nbuck)
{
    __shared__ int tmp[MAX_BUCKETS];
    int tid = threadIdx.x;
    int v = (tid < nbuck) ? hist[tid] : 0;
    tmp[tid] = v;
    __syncthreads();
#pragma unroll
    for (int d = 1; d < MAX_BUCKETS; d <<= 1) {
        int t2 = (tid >= d) ? tmp[tid - d] : 0;
        __syncthreads();
        tmp[tid] += t2;
        __syncthreads();
    }
    if (tid < nbuck) cursor[tid] = tmp[tid] - v;   // exclusive prefix
}

__global__ __launch_bounds__(256) void scatter_kernel(
    const int* __restrict__ src, const int* __restrict__ dst,
    int* __restrict__ cursor,
    int* __restrict__ ssrc, int* __restrict__ sdst, int* __restrict__ seid,
    int n_edges)
{
    int e = blockIdx.x * blockDim.x + threadIdx.x;
    if (e >= n_edges) return;
    int s = src[e];
    int p = atomicAdd(&cursor[s >> BUCKET_SHIFT], 1);
    ssrc[p] = s;
    sdst[p] = dst[e];
    seid[p] = e;
}

// ---- Pass 2: MLP over sorted edges, bijective XCD swizzle ----
__global__ __launch_bounds__(256) void edge_mlp_sorted_kernel(
    const __half* __restrict__ hh,
    const int*   __restrict__ ssrc,
    const int*   __restrict__ sdst,
    const int*   __restrict__ seid,
    const float* __restrict__ W1,   // [128][32]
    const float* __restrict__ b1,
    const float* __restrict__ W2,
    const float* __restrict__ b2,
    float*       __restrict__ out,
    int n_edges, int nblocks)
{
    // HW dispatch round-robins blocks over 8 XCDs (b % 8). Remap so each
    // XCD works a CONTIGUOUS range of the sorted edge list -> its L2 keeps
    // the current src-bucket rows resident. Bijective for any nblocks (m204).
    int bid = blockIdx.x;
    int q = nblocks >> 3, r = nblocks & 7;
    int xcd = bid & 7, idx = bid >> 3;
    int chunk = (xcd < r) ? (xcd * (q + 1) + idx)
                          : (r * (q + 1) + (xcd - r) * q + idx);
    int t = chunk * 256 + (int)threadIdx.x;
    if (t >= n_edges) return;

    const __half* hs = hh + (size_t)ssrc[t] * H_FEATS;
    const __half* hd = hh + (size_t)sdst[t] * H_FEATS;

    float hidden[HIDDEN];
#pragma unroll
    for (int j = 0; j < HIDDEN; ++j) hidden[j] = b1[j];

#pragma unroll 2
    for (int f0 = 0; f0 < H_FEATS; f0 += 8) {
        H8 A, B;
        A.u = *reinterpret_cast<const uint4*>(hs + f0);
        B.u = *reinterpret_cast<const uint4*>(hd + f0);
        float he[8];
#pragma unroll
        for (int k = 0; k < 4; ++k) {
            float2 a = __half22float2(A.h2[k]);
            float2 b = __half22float2(B.h2[k]);
            he[2 * k]     = a.x * b.x;
            he[2 * k + 1] = a.y * b.y;
        }
        const float* w = W1 + (size_t)f0 * HIDDEN;
#pragma unroll
        for (int j = 0; j < HIDDEN; ++j) {
            float acc = hidden[j];
#pragma unroll
            for (int k = 0; k < 8; ++k)
                acc = fmaf(he[k], w[(size_t)k * HIDDEN + j], acc);
            hidden[j] = acc;
        }
    }

    float score = b2[0];
#pragma unroll
    for (int j = 0; j < HIDDEN; ++j) {
        float rr = hidden[j] > 0.0f ? hidden[j] : 0.0f;
        score = fmaf(rr, W2[j], score);
    }
    out[seid[t]] = score;
}

// ---- Fallback: unsorted fp16 path (ws holds only hh) ----
__global__ __launch_bounds__(256) void edge_mlp_fp16_kernel(
    const __half* __restrict__ hh,
    const int*   __restrict__ src,
    const int*   __restrict__ dst,
    const float* __restrict__ W1,
    const float* __restrict__ b1,
    const float* __restrict__ W2,
    const float* __restrict__ b2,
    float*       __restrict__ out,
    int n_edges)
{
    int e = blockIdx.x * blockDim.x + threadIdx.x;
    if (e >= n_edges) return;

    const __half* hs = hh + (size_t)src[e] * H_FEATS;
    const __half* hd = hh + (size_t)dst[e] * H_FEATS;

    float hidden[HIDDEN];
#pragma unroll
    for (int j = 0; j < HIDDEN; ++j) hidden[j] = b1[j];

#pragma unroll 2
    for (int f0 = 0; f0 < H_FEATS; f0 += 8) {
        H8 A, B;
        A.u = *reinterpret_cast<const uint4*>(hs + f0);
        B.u = *reinterpret_cast<const uint4*>(hd + f0);
        float he[8];
#pragma unroll
        for (int k = 0; k < 4; ++k) {
            float2 a = __half22float2(A.h2[k]);
            float2 b = __half22float2(B.h2[k]);
            he[2 * k]     = a.x * b.x;
            he[2 * k + 1] = a.y * b.y;
        }
        const float* w = W1 + (size_t)f0 * HIDDEN;
#pragma unroll
        for (int j = 0; j < HIDDEN; ++j) {
            float acc = hidden[j];
#pragma unroll
            for (int k = 0; k < 8; ++k)
                acc = fmaf(he[k], w[(size_t)k * HIDDEN + j], acc);
            hidden[j] = acc;
        }
    }

    float score = b2[0];
#pragma unroll
    for (int j = 0; j < HIDDEN; ++j) {
        float r = hidden[j] > 0.0f ? hidden[j] : 0.0f;
        score = fmaf(r, W2[j], score);
    }
    out[e] = score;
}

// ---- Fallback: fp32 path (tiny ws) ----
__global__ __launch_bounds__(256) void edge_mlp_kernel(
    const float* __restrict__ h,
    const int*   __restrict__ src,
    const int*   __restrict__ dst,
    const float* __restrict__ W1,
    const float* __restrict__ b1,
    const float* __restrict__ W2,
    const float* __restrict__ b2,
    float*       __restrict__ out,
    int n_edges)
{
    int e = blockIdx.x * blockDim.x + threadIdx.x;
    if (e >= n_edges) return;

    const float* hs = h + (size_t)src[e] * H_FEATS;
    const float* hd = h + (size_t)dst[e] * H_FEATS;

    float hidden[HIDDEN];
#pragma unroll
    for (int j = 0; j < HIDDEN; ++j) hidden[j] = b1[j];

#pragma unroll 4
    for (int f0 = 0; f0 < H_FEATS; f0 += 4) {
        float4 a = *reinterpret_cast<const float4*>(hs + f0);
        float4 b = *reinterpret_cast<const float4*>(hd + f0);
        float he0 = a.x * b.x, he1 = a.y * b.y, he2 = a.z * b.z, he3 = a.w * b.w;
        const float* w0 = W1 + (size_t)(f0 + 0) * HIDDEN;
        const float* w1 = W1 + (size_t)(f0 + 1) * HIDDEN;
        const float* w2 = W1 + (size_t)(f0 + 2) * HIDDEN;
        const float* w3 = W1 + (size_t)(f0 + 3) * HIDDEN;
#pragma unroll
        for (int j = 0; j < HIDDEN; ++j) {
            float acc = hidden[j];
            acc = fmaf(he0, w0[j], acc);
            acc = fmaf(he1, w1[j], acc);
            acc = fmaf(he2, w2[j], acc);
            acc = fmaf(he3, w3[j], acc);
            hidden[j] = acc;
        }
    }

    float score = b2[0];
#pragma unroll
    for (int j = 0; j < HIDDEN; ++j) {
        float r = hidden[j] > 0.0f ? hidden[j] : 0.0f;
        score = fmaf(r, W2[j], score);
    }
    out[e] = score;
}

extern "C" void kernel_launch(void* const* d_in, const int* in_sizes, int n_in,
                              void* d_out, int out_size, void* d_ws, size_t ws_size,
                              hipStream_t stream) {
    const float* h   = (const float*)d_in[0];
    const int*   src = (const int*)  d_in[1];
    const int*   dst = (const int*)  d_in[2];
    const float* W1  = (const float*)d_in[3];
    const float* b1  = (const float*)d_in[4];
    const float* W2  = (const float*)d_in[5];
    const float* b2  = (const float*)d_in[6];
    float* out = (float*)d_out;

    int n_node_feats = in_sizes[0];            // N * 128
    int n_edges = in_sizes[1];
    int n_nodes = n_node_feats / H_FEATS;
    int nbuck = (n_nodes + (1 << BUCKET_SHIFT) - 1) >> BUCKET_SHIFT;

    const int block = 256;
    int egrid = (n_edges + block - 1) / block;

    // ws layout (256B aligned)
    size_t hh_bytes   = (size_t)n_node_feats * sizeof(__half);
    size_t off_ssrc   = (hh_bytes + 255) & ~(size_t)255;
    size_t off_sdst   = off_ssrc + (size_t)n_edges * 4;
    size_t off_seid   = off_sdst + (size_t)n_edges * 4;
    size_t off_hist   = off_seid + (size_t)n_edges * 4;
    size_t off_cursor = off_hist + (size_t)nbuck * 4;
    size_t need_full  = off_cursor + (size_t)nbuck * 4;

    if (ws_size >= need_full && nbuck <= MAX_BUCKETS) {
        char* ws = (char*)d_ws;
        __half* hh  = (__half*)ws;
        int* ssrc   = (int*)(ws + off_ssrc);
        int* sdst   = (int*)(ws + off_sdst);
        int* seid   = (int*)(ws + off_seid);
        int* hist   = (int*)(ws + off_hist);
        int* cursor = (int*)(ws + off_cursor);

        int n8 = n_node_feats / 8;
        convert_h_kernel<<<(n8 + block - 1) / block, block, 0, stream>>>(h, hh, n8);
        zero_hist_kernel<<<(nbuck + block - 1) / block, block, 0, stream>>>(hist, nbuck);
        hist_kernel<<<egrid, block, 0, stream>>>(src, hist, n_edges);
        scan_kernel<<<1, MAX_BUCKETS, 0, stream>>>(hist, cursor, nbuck);
        scatter_kernel<<<egrid, block, 0, stream>>>(src, dst, cursor,
                                                    ssrc, sdst, seid, n_edges);
        edge_mlp_sorted_kernel<<<egrid, block, 0, stream>>>(hh, ssrc, sdst, seid,
                                                            W1, b1, W2, b2, out,
                                                            n_edges, egrid);
    } else if (ws_size >= hh_bytes) {
        __half* hh = (__half*)d_ws;
        int n8 = n_node_feats / 8;
        convert_h_kernel<<<(n8 + block - 1) / block, block, 0, stream>>>(h, hh, n8);
        edge_mlp_fp16_kernel<<<egrid, block, 0, stream>>>(hh, src, dst,
                                                          W1, b1, W2, b2, out, n_edges);
    } else {
        edge_mlp_kernel<<<egrid, block, 0, stream>>>(h, src, dst,
                                                     W1, b1, W2, b2, out, n_edges);
    }
}

// Round 5
// 253.219 us; speedup vs baseline: 3.7674x; 3.7674x over previous
//
#include <hip/hip_runtime.h>
#include <hip/hip_bf16.h>
#include <hip/hip_fp16.h>

#define H_FEATS 128
#define HIDDEN  32
#define BUCKET_SHIFT 9            // 512 nodes/bucket = 128KB fp16
#define MAX_BUCKETS 1024
#define SORT_EPB 4096             // edges per block in sort passes (256 thr x 16)

union H8 { uint4 u; __half2 h2[4]; };

// ---- Pass 1: h (fp32) -> fp16 rows in ws ----
__global__ __launch_bounds__(256) void convert_h_kernel(
    const float* __restrict__ h, __half* __restrict__ hh, int n8)
{
    int i = blockIdx.x * blockDim.x + threadIdx.x;
    if (i >= n8) return;
    const float4* s = reinterpret_cast<const float4*>(h) + (size_t)i * 2;
    float4 a = s[0], b = s[1];
    H8 r;
    r.h2[0] = __floats2half2_rn(a.x, a.y);
    r.h2[1] = __floats2half2_rn(a.z, a.w);
    r.h2[2] = __floats2half2_rn(b.x, b.y);
    r.h2[3] = __floats2half2_rn(b.z, b.w);
    reinterpret_cast<uint4*>(hh)[i] = r.u;
}

// ---- Sort pass A: per-block LDS histogram -> blockhist[bucket][block] ----
__global__ __launch_bounds__(256) void hist_kernel(
    const int* __restrict__ src, int* __restrict__ blockhist,
    int n_edges, int nbuck, int nblocks)
{
    __shared__ int lh[MAX_BUCKETS];
    int tid = threadIdx.x;
    for (int i = tid; i < nbuck; i += 256) lh[i] = 0;
    __syncthreads();
    int ebase = blockIdx.x * SORT_EPB;
#pragma unroll
    for (int k = 0; k < SORT_EPB / 256; ++k) {
        int e = ebase + k * 256 + tid;
        if (e < n_edges) atomicAdd(&lh[src[e] >> BUCKET_SHIFT], 1);  // LDS atomic
    }
    __syncthreads();
    for (int i = tid; i < nbuck; i += 256)
        blockhist[(size_t)i * nblocks + blockIdx.x] = lh[i];
}

// ---- Sort pass B1: exclusive scan each bucket-row across blocks ----
__global__ __launch_bounds__(256) void scan_rows_kernel(
    int* __restrict__ blockhist, int* __restrict__ rowsum, int nblocks)
{
    __shared__ int tmp[256];
    int row = blockIdx.x;
    int tid = threadIdx.x;
    size_t rowbase = (size_t)row * nblocks;
    int carry = 0;
    for (int c = 0; c < nblocks; c += 256) {
        int idx = c + tid;
        int v = (idx < nblocks) ? blockhist[rowbase + idx] : 0;
        tmp[tid] = v;
        __syncthreads();
#pragma unroll
        for (int d = 1; d < 256; d <<= 1) {
            int t = (tid >= d) ? tmp[tid - d] : 0;
            __syncthreads();
            tmp[tid] += t;
            __syncthreads();
        }
        int incl = tmp[tid];
        if (idx < nblocks) blockhist[rowbase + idx] = carry + incl - v;
        carry += tmp[255];
        __syncthreads();
    }
    if (tid == 0) rowsum[row] = carry;
}

// ---- Sort pass B2: exclusive scan of bucket totals -> base ----
__global__ __launch_bounds__(MAX_BUCKETS) void scan_base_kernel(
    const int* __restrict__ rowsum, int* __restrict__ base, int nbuck)
{
    __shared__ int tmp[MAX_BUCKETS];
    int tid = threadIdx.x;
    int v = (tid < nbuck) ? rowsum[tid] : 0;
    tmp[tid] = v;
    __syncthreads();
#pragma unroll
    for (int d = 1; d < MAX_BUCKETS; d <<= 1) {
        int t = (tid >= d) ? tmp[tid - d] : 0;
        __syncthreads();
        tmp[tid] += t;
        __syncthreads();
    }
    if (tid < nbuck) base[tid] = tmp[tid] - v;
}

// ---- Sort pass C: place edges via LDS cursors (no global atomics) ----
__global__ __launch_bounds__(256) void scatter_kernel(
    const int* __restrict__ src, const int* __restrict__ dst,
    const int* __restrict__ blockhist, const int* __restrict__ base,
    int* __restrict__ ssrc, int* __restrict__ sdst, int* __restrict__ seid,
    int n_edges, int nbuck, int nblocks)
{
    __shared__ int lcur[MAX_BUCKETS];
    int tid = threadIdx.x;
    for (int i = tid; i < nbuck; i += 256)
        lcur[i] = base[i] + blockhist[(size_t)i * nblocks + blockIdx.x];
    __syncthreads();
    int ebase = blockIdx.x * SORT_EPB;
#pragma unroll
    for (int k = 0; k < SORT_EPB / 256; ++k) {
        int e = ebase + k * 256 + tid;
        if (e < n_edges) {
            int s = src[e];
            int p = atomicAdd(&lcur[s >> BUCKET_SHIFT], 1);   // LDS atomic
            ssrc[p] = s;
            sdst[p] = dst[e];
            seid[p] = e;
        }
    }
}

// ---- MLP over sorted edges, bijective XCD chunking ----
__global__ __launch_bounds__(256) void edge_mlp_sorted_kernel(
    const __half* __restrict__ hh,
    const int*   __restrict__ ssrc,
    const int*   __restrict__ sdst,
    const int*   __restrict__ seid,
    const float* __restrict__ W1,   // [128][32]
    const float* __restrict__ b1,
    const float* __restrict__ W2,
    const float* __restrict__ b2,
    float*       __restrict__ out,
    int n_edges, int nblocks)
{
    // Contiguous sorted-edge range per XCD -> src bucket stays L2-resident.
    int bid = blockIdx.x;
    int q = nblocks >> 3, r = nblocks & 7;
    int xcd = bid & 7, idx = bid >> 3;
    int chunk = (xcd < r) ? (xcd * (q + 1) + idx)
                          : (r * (q + 1) + (xcd - r) * q + idx);
    int t = chunk * 256 + (int)threadIdx.x;
    if (t >= n_edges) return;

    const __half* hs = hh + (size_t)ssrc[t] * H_FEATS;
    const __half* hd = hh + (size_t)sdst[t] * H_FEATS;

    float hidden[HIDDEN];
#pragma unroll
    for (int j = 0; j < HIDDEN; ++j) hidden[j] = b1[j];

#pragma unroll 2
    for (int f0 = 0; f0 < H_FEATS; f0 += 8) {
        H8 A, B;
        A.u = *reinterpret_cast<const uint4*>(hs + f0);
        B.u = *reinterpret_cast<const uint4*>(hd + f0);
        float he[8];
#pragma unroll
        for (int k = 0; k < 4; ++k) {
            float2 a = __half22float2(A.h2[k]);
            float2 b = __half22float2(B.h2[k]);
            he[2 * k]     = a.x * b.x;
            he[2 * k + 1] = a.y * b.y;
        }
        const float* w = W1 + (size_t)f0 * HIDDEN;
#pragma unroll
        for (int j = 0; j < HIDDEN; ++j) {
            float acc = hidden[j];
#pragma unroll
            for (int k = 0; k < 8; ++k)
                acc = fmaf(he[k], w[(size_t)k * HIDDEN + j], acc);
            hidden[j] = acc;
        }
    }

    float score = b2[0];
#pragma unroll
    for (int j = 0; j < HIDDEN; ++j) {
        float rr = hidden[j] > 0.0f ? hidden[j] : 0.0f;
        score = fmaf(rr, W2[j], score);
    }
    out[seid[t]] = score;
}

// ---- Fallback: unsorted fp16 path ----
__global__ __launch_bounds__(256) void edge_mlp_fp16_kernel(
    const __half* __restrict__ hh,
    const int*   __restrict__ src,
    const int*   __restrict__ dst,
    const float* __restrict__ W1,
    const float* __restrict__ b1,
    const float* __restrict__ W2,
    const float* __restrict__ b2,
    float*       __restrict__ out,
    int n_edges)
{
    int e = blockIdx.x * blockDim.x + threadIdx.x;
    if (e >= n_edges) return;

    const __half* hs = hh + (size_t)src[e] * H_FEATS;
    const __half* hd = hh + (size_t)dst[e] * H_FEATS;

    float hidden[HIDDEN];
#pragma unroll
    for (int j = 0; j < HIDDEN; ++j) hidden[j] = b1[j];

#pragma unroll 2
    for (int f0 = 0; f0 < H_FEATS; f0 += 8) {
        H8 A, B;
        A.u = *reinterpret_cast<const uint4*>(hs + f0);
        B.u = *reinterpret_cast<const uint4*>(hd + f0);
        float he[8];
#pragma unroll
        for (int k = 0; k < 4; ++k) {
            float2 a = __half22float2(A.h2[k]);
            float2 b = __half22float2(B.h2[k]);
            he[2 * k]     = a.x * b.x;
            he[2 * k + 1] = a.y * b.y;
        }
        const float* w = W1 + (size_t)f0 * HIDDEN;
#pragma unroll
        for (int j = 0; j < HIDDEN; ++j) {
            float acc = hidden[j];
#pragma unroll
            for (int k = 0; k < 8; ++k)
                acc = fmaf(he[k], w[(size_t)k * HIDDEN + j], acc);
            hidden[j] = acc;
        }
    }

    float score = b2[0];
#pragma unroll
    for (int j = 0; j < HIDDEN; ++j) {
        float r = hidden[j] > 0.0f ? hidden[j] : 0.0f;
        score = fmaf(r, W2[j], score);
    }
    out[e] = score;
}

// ---- Fallback: fp32 path (tiny ws) ----
__global__ __launch_bounds__(256) void edge_mlp_kernel(
    const float* __restrict__ h,
    const int*   __restrict__ src,
    const int*   __restrict__ dst,
    const float* __restrict__ W1,
    const float* __restrict__ b1,
    const float* __restrict__ W2,
    const float* __restrict__ b2,
    float*       __restrict__ out,
    int n_edges)
{
    int e = blockIdx.x * blockDim.x + threadIdx.x;
    if (e >= n_edges) return;

    const float* hs = h + (size_t)src[e] * H_FEATS;
    const float* hd = h + (size_t)dst[e] * H_FEATS;

    float hidden[HIDDEN];
#pragma unroll
    for (int j = 0; j < HIDDEN; ++j) hidden[j] = b1[j];

#pragma unroll 4
    for (int f0 = 0; f0 < H_FEATS; f0 += 4) {
        float4 a = *reinterpret_cast<const float4*>(hs + f0);
        float4 b = *reinterpret_cast<const float4*>(hd + f0);
        float he0 = a.x * b.x, he1 = a.y * b.y, he2 = a.z * b.z, he3 = a.w * b.w;
        const float* w0 = W1 + (size_t)(f0 + 0) * HIDDEN;
        const float* w1 = W1 + (size_t)(f0 + 1) * HIDDEN;
        const float* w2 = W1 + (size_t)(f0 + 2) * HIDDEN;
        const float* w3 = W1 + (size_t)(f0 + 3) * HIDDEN;
#pragma unroll
        for (int j = 0; j < HIDDEN; ++j) {
            float acc = hidden[j];
            acc = fmaf(he0, w0[j], acc);
            acc = fmaf(he1, w1[j], acc);
            acc = fmaf(he2, w2[j], acc);
            acc = fmaf(he3, w3[j], acc);
            hidden[j] = acc;
        }
    }

    float score = b2[0];
#pragma unroll
    for (int j = 0; j < HIDDEN; ++j) {
        float r = hidden[j] > 0.0f ? hidden[j] : 0.0f;
        score = fmaf(r, W2[j], score);
    }
    out[e] = score;
}

extern "C" void kernel_launch(void* const* d_in, const int* in_sizes, int n_in,
                              void* d_out, int out_size, void* d_ws, size_t ws_size,
                              hipStream_t stream) {
    const float* h   = (const float*)d_in[0];
    const int*   src = (const int*)  d_in[1];
    const int*   dst = (const int*)  d_in[2];
    const float* W1  = (const float*)d_in[3];
    const float* b1  = (const float*)d_in[4];
    const float* W2  = (const float*)d_in[5];
    const float* b2  = (const float*)d_in[6];
    float* out = (float*)d_out;

    int n_node_feats = in_sizes[0];            // N * 128
    int n_edges = in_sizes[1];
    int n_nodes = n_node_feats / H_FEATS;
    int nbuck = (n_nodes + (1 << BUCKET_SHIFT) - 1) >> BUCKET_SHIFT;

    const int block = 256;
    int egrid  = (n_edges + block - 1) / block;          // MLP grid
    int sgrid  = (n_edges + SORT_EPB - 1) / SORT_EPB;    // sort-pass grid

    // ws layout (256B aligned)
    size_t hh_bytes  = (size_t)n_node_feats * sizeof(__half);
    size_t off_ssrc  = (hh_bytes + 255) & ~(size_t)255;
    size_t off_sdst  = off_ssrc + (size_t)n_edges * 4;
    size_t off_seid  = off_sdst + (size_t)n_edges * 4;
    size_t off_bh    = off_seid + (size_t)n_edges * 4;
    size_t off_rsum  = off_bh + (size_t)nbuck * sgrid * 4;
    size_t off_base  = off_rsum + (size_t)MAX_BUCKETS * 4;
    size_t need_full = off_base + (size_t)MAX_BUCKETS * 4;

    if (ws_size >= need_full && nbuck <= MAX_BUCKETS) {
        char* ws = (char*)d_ws;
        __half* hh    = (__half*)ws;
        int* ssrc     = (int*)(ws + off_ssrc);
        int* sdst     = (int*)(ws + off_sdst);
        int* seid     = (int*)(ws + off_seid);
        int* blockhist= (int*)(ws + off_bh);
        int* rowsum   = (int*)(ws + off_rsum);
        int* base     = (int*)(ws + off_base);

        int n8 = n_node_feats / 8;
        convert_h_kernel<<<(n8 + block - 1) / block, block, 0, stream>>>(h, hh, n8);
        hist_kernel<<<sgrid, block, 0, stream>>>(src, blockhist, n_edges, nbuck, sgrid);
        scan_rows_kernel<<<nbuck, block, 0, stream>>>(blockhist, rowsum, sgrid);
        scan_base_kernel<<<1, MAX_BUCKETS, 0, stream>>>(rowsum, base, nbuck);
        scatter_kernel<<<sgrid, block, 0, stream>>>(src, dst, blockhist, base,
                                                    ssrc, sdst, seid,
                                                    n_edges, nbuck, sgrid);
        edge_mlp_sorted_kernel<<<egrid, block, 0, stream>>>(hh, ssrc, sdst, seid,
                                                            W1, b1, W2, b2, out,
                                                            n_edges, egrid);
    } else if (ws_size >= hh_bytes) {
        __half* hh = (__half*)d_ws;
        int n8 = n_node_feats / 8;
        convert_h_kernel<<<(n8 + block - 1) / block, block, 0, stream>>>(h, hh, n8);
        edge_mlp_fp16_kernel<<<egrid, block, 0, stream>>>(hh, src, dst,
                                                          W1, b1, W2, b2, out, n_edges);
    } else {
        edge_mlp_kernel<<<egrid, block, 0, stream>>>(h, src, dst,
                                                     W1, b1, W2, b2, out, n_edges);
    }
}

// Round 6
// 188.269 us; speedup vs baseline: 5.0671x; 1.3450x over previous
//
#include <hip/hip_runtime.h>
#include <hip/hip_bf16.h>
#include <hip/hip_fp16.h>

#define H_FEATS 128
#define HIDDEN  32
#define BUCKET_SHIFT 9            // 512 nodes/bucket = 256KB fp16 window
#define MAX_BUCKETS 1024
#define SORT_EPB 4096             // edges per block in sort passes

typedef _Float16 f16x8 __attribute__((ext_vector_type(8)));
typedef float    f32x4 __attribute__((ext_vector_type(4)));

union H8 { uint4 u; __half2 h2[4]; };
union U16 { uint4 u; f16x8 h; };

// ---- Pass 1a: h (fp32) -> fp16 rows in ws ----
__global__ __launch_bounds__(256) void convert_h_kernel(
    const float* __restrict__ h, __half* __restrict__ hh, int n8)
{
    int i = blockIdx.x * blockDim.x + threadIdx.x;
    if (i >= n8) return;
    const float4* s = reinterpret_cast<const float4*>(h) + (size_t)i * 2;
    float4 a = s[0], b = s[1];
    H8 r;
    r.h2[0] = __floats2half2_rn(a.x, a.y);
    r.h2[1] = __floats2half2_rn(a.z, a.w);
    r.h2[2] = __floats2half2_rn(b.x, b.y);
    r.h2[3] = __floats2half2_rn(b.z, b.w);
    reinterpret_cast<uint4*>(hh)[i] = r.u;
}

// ---- Pass 1b: W1[128][32] fp32 -> W1T[32][128] fp16 (B-operand friendly) ----
__global__ __launch_bounds__(256) void convert_w_kernel(
    const float* __restrict__ W1, __half* __restrict__ w1t)
{
    int t = blockIdx.x * 256 + threadIdx.x;     // 4096 threads total
    if (t >= H_FEATS * HIDDEN) return;
    int k = t >> 5, n = t & 31;
    w1t[(size_t)n * H_FEATS + k] = __float2half(W1[t]);
}

// ---- Sort pass A: per-block LDS histogram -> blockhist[bucket][block] ----
__global__ __launch_bounds__(256) void hist_kernel(
    const int* __restrict__ src, int* __restrict__ blockhist,
    int n_edges, int nbuck, int nblocks)
{
    __shared__ int lh[MAX_BUCKETS];
    int tid = threadIdx.x;
    for (int i = tid; i < nbuck; i += 256) lh[i] = 0;
    __syncthreads();
    int ebase = blockIdx.x * SORT_EPB;
#pragma unroll
    for (int k = 0; k < SORT_EPB / 256; ++k) {
        int e = ebase + k * 256 + tid;
        if (e < n_edges) atomicAdd(&lh[src[e] >> BUCKET_SHIFT], 1);  // LDS atomic
    }
    __syncthreads();
    for (int i = tid; i < nbuck; i += 256)
        blockhist[(size_t)i * nblocks + blockIdx.x] = lh[i];
}

// ---- Sort pass B1: exclusive scan each bucket-row across blocks ----
__global__ __launch_bounds__(256) void scan_rows_kernel(
    int* __restrict__ blockhist, int* __restrict__ rowsum, int nblocks)
{
    __shared__ int tmp[256];
    int row = blockIdx.x;
    int tid = threadIdx.x;
    size_t rowbase = (size_t)row * nblocks;
    int carry = 0;
    for (int c = 0; c < nblocks; c += 256) {
        int idx = c + tid;
        int v = (idx < nblocks) ? blockhist[rowbase + idx] : 0;
        tmp[tid] = v;
        __syncthreads();
#pragma unroll
        for (int d = 1; d < 256; d <<= 1) {
            int t = (tid >= d) ? tmp[tid - d] : 0;
            __syncthreads();
            tmp[tid] += t;
            __syncthreads();
        }
        int incl = tmp[tid];
        if (idx < nblocks) blockhist[rowbase + idx] = carry + incl - v;
        carry += tmp[255];
        __syncthreads();
    }
    if (tid == 0) rowsum[row] = carry;
}

// ---- Sort pass B2: exclusive scan of bucket totals -> base ----
__global__ __launch_bounds__(MAX_BUCKETS) void scan_base_kernel(
    const int* __restrict__ rowsum, int* __restrict__ base, int nbuck)
{
    __shared__ int tmp[MAX_BUCKETS];
    int tid = threadIdx.x;
    int v = (tid < nbuck) ? rowsum[tid] : 0;
    tmp[tid] = v;
    __syncthreads();
#pragma unroll
    for (int d = 1; d < MAX_BUCKETS; d <<= 1) {
        int t = (tid >= d) ? tmp[tid - d] : 0;
        __syncthreads();
        tmp[tid] += t;
        __syncthreads();
    }
    if (tid < nbuck) base[tid] = tmp[tid] - v;
}

// ---- Sort pass C: place edges via LDS cursors (no global atomics) ----
__global__ __launch_bounds__(256) void scatter_kernel(
    const int* __restrict__ src, const int* __restrict__ dst,
    const int* __restrict__ blockhist, const int* __restrict__ base,
    int2* __restrict__ spair, int* __restrict__ seid,
    int n_edges, int nbuck, int nblocks)
{
    __shared__ int lcur[MAX_BUCKETS];
    int tid = threadIdx.x;
    for (int i = tid; i < nbuck; i += 256)
        lcur[i] = base[i] + blockhist[(size_t)i * nblocks + blockIdx.x];
    __syncthreads();
    int ebase = blockIdx.x * SORT_EPB;
#pragma unroll
    for (int k = 0; k < SORT_EPB / 256; ++k) {
        int e = ebase + k * 256 + tid;
        if (e < n_edges) {
            int s = src[e];
            int p = atomicAdd(&lcur[s >> BUCKET_SHIFT], 1);   // LDS atomic
            spair[p] = make_int2(s, dst[e]);
            seid[p] = e;
        }
    }
}

// ---- MFMA MLP over sorted edges ----
// Per wave: 4 groups of 16 edges. A = he[16 x 128] (fp16, in regs from the
// gather), B = W1T fragments (regs, L2-served), D = hidden[16 x 32] (f32).
// Frag layouts (ref-verified family, learn_hip m89/m92/m93):
//   A: row = lane&15, k = (lane>>4)*8 + j  (8 contiguous halves = 1 uint4)
//   B: col = lane&15, k = (lane>>4)*8 + j
//   D: col = lane&15, row = (lane>>4)*4 + reg
__global__ __launch_bounds__(256) void edge_mlp_mfma_kernel(
    const __half* __restrict__ hh,
    const __half* __restrict__ w1t,    // [32][128] fp16
    const int2*  __restrict__ spair,   // sorted (src,dst)
    const int*   __restrict__ seid,    // sorted -> original edge id
    const float* __restrict__ b1,
    const float* __restrict__ W2,
    const float* __restrict__ b2,
    float*       __restrict__ out,
    int n_edges, int nblocks)
{
    // Bijective XCD chunking: contiguous sorted range per XCD -> src rows L2-hit.
    int bid = blockIdx.x;
    int q8 = nblocks >> 3, r8 = nblocks & 7;
    int xcd = bid & 7, idx = bid >> 3;
    int chunk = (xcd < r8) ? (xcd * (q8 + 1) + idx)
                           : (r8 * (q8 + 1) + (xcd - r8) * q8 + idx);
    int tile = chunk * 256;

    int lane = (int)(threadIdx.x & 63);
    int wv   = (int)(threadIdx.x >> 6);
    int m    = lane & 15;     // A-row / B-col / D-col
    int kq   = lane >> 4;     // k-quad

    // B fragments: bfrag[nt][s] covers cols 16*nt+m, k = 32*s + kq*8 + [0..8)
    f16x8 bfrag[2][4];
#pragma unroll
    for (int nt = 0; nt < 2; ++nt)
#pragma unroll
        for (int s = 0; s < 4; ++s) {
            U16 t;
            t.u = *reinterpret_cast<const uint4*>(
                w1t + (size_t)(nt * 16 + m) * H_FEATS + s * 32 + kq * 8);
            bfrag[nt][s] = t.h;
        }

    float b1f0 = b1[m],  b1f1 = b1[m + 16];
    float w2f0 = W2[m],  w2f1 = W2[m + 16];
    float b2f  = b2[0];

#pragma unroll
    for (int g = 0; g < 4; ++g) {
        int t0 = tile + wv * 64 + g * 16;
        int eidx = t0 + m;
        int ecl  = eidx < n_edges ? eidx : n_edges - 1;
        int2 sp  = spair[ecl];
        const __half* hs = hh + (size_t)sp.x * H_FEATS;
        const __half* hd = hh + (size_t)sp.y * H_FEATS;

        f32x4 acc0 = {0.f, 0.f, 0.f, 0.f};
        f32x4 acc1 = {0.f, 0.f, 0.f, 0.f};
#pragma unroll
        for (int s = 0; s < 4; ++s) {
            U16 a, b;
            a.u = *reinterpret_cast<const uint4*>(hs + s * 32 + kq * 8);
            b.u = *reinterpret_cast<const uint4*>(hd + s * 32 + kq * 8);
            f16x8 he = a.h * b.h;   // packed fp16 multiplies
            acc0 = __builtin_amdgcn_mfma_f32_16x16x32_f16(he, bfrag[0][s], acc0, 0, 0, 0);
            acc1 = __builtin_amdgcn_mfma_f32_16x16x32_f16(he, bfrag[1][s], acc1, 0, 0, 0);
        }

        // Epilogue: bias + ReLU + W2 dot, reduce over the 16-lane col group.
        float sc[4];
#pragma unroll
        for (int r = 0; r < 4; ++r) {
            float h0 = acc0[r] + b1f0; h0 = h0 > 0.f ? h0 : 0.f;
            float h1 = acc1[r] + b1f1; h1 = h1 > 0.f ? h1 : 0.f;
            float p = fmaf(h0, w2f0, h1 * w2f1);
#pragma unroll
            for (int d = 1; d < 16; d <<= 1)
                p += __shfl_xor(p, d, 64);
            sc[r] = p + b2f;
        }
        if (m == 0) {
            int e0 = t0 + kq * 4;
#pragma unroll
            for (int r = 0; r < 4; ++r) {
                int ee = e0 + r;
                if (ee < n_edges) out[seid[ee]] = sc[r];
            }
        }
    }
}

// ---- Fallback: unsorted fp16 scalar path ----
__global__ __launch_bounds__(256) void edge_mlp_fp16_kernel(
    const __half* __restrict__ hh,
    const int*   __restrict__ src,
    const int*   __restrict__ dst,
    const float* __restrict__ W1,
    const float* __restrict__ b1,
    const float* __restrict__ W2,
    const float* __restrict__ b2,
    float*       __restrict__ out,
    int n_edges)
{
    int e = blockIdx.x * blockDim.x + threadIdx.x;
    if (e >= n_edges) return;

    const __half* hs = hh + (size_t)src[e] * H_FEATS;
    const __half* hd = hh + (size_t)dst[e] * H_FEATS;

    float hidden[HIDDEN];
#pragma unroll
    for (int j = 0; j < HIDDEN; ++j) hidden[j] = b1[j];

#pragma unroll 2
    for (int f0 = 0; f0 < H_FEATS; f0 += 8) {
        H8 A, B;
        A.u = *reinterpret_cast<const uint4*>(hs + f0);
        B.u = *reinterpret_cast<const uint4*>(hd + f0);
        float he[8];
#pragma unroll
        for (int k = 0; k < 4; ++k) {
            float2 a = __half22float2(A.h2[k]);
            float2 b = __half22float2(B.h2[k]);
            he[2 * k]     = a.x * b.x;
            he[2 * k + 1] = a.y * b.y;
        }
        const float* w = W1 + (size_t)f0 * HIDDEN;
#pragma unroll
        for (int j = 0; j < HIDDEN; ++j) {
            float acc = hidden[j];
#pragma unroll
            for (int k = 0; k < 8; ++k)
                acc = fmaf(he[k], w[(size_t)k * HIDDEN + j], acc);
            hidden[j] = acc;
        }
    }

    float score = b2[0];
#pragma unroll
    for (int j = 0; j < HIDDEN; ++j) {
        float r = hidden[j] > 0.0f ? hidden[j] : 0.0f;
        score = fmaf(r, W2[j], score);
    }
    out[e] = score;
}

// ---- Fallback: fp32 path (tiny ws) ----
__global__ __launch_bounds__(256) void edge_mlp_kernel(
    const float* __restrict__ h,
    const int*   __restrict__ src,
    const int*   __restrict__ dst,
    const float* __restrict__ W1,
    const float* __restrict__ b1,
    const float* __restrict__ W2,
    const float* __restrict__ b2,
    float*       __restrict__ out,
    int n_edges)
{
    int e = blockIdx.x * blockDim.x + threadIdx.x;
    if (e >= n_edges) return;

    const float* hs = h + (size_t)src[e] * H_FEATS;
    const float* hd = h + (size_t)dst[e] * H_FEATS;

    float hidden[HIDDEN];
#pragma unroll
    for (int j = 0; j < HIDDEN; ++j) hidden[j] = b1[j];

#pragma unroll 4
    for (int f0 = 0; f0 < H_FEATS; f0 += 4) {
        float4 a = *reinterpret_cast<const float4*>(hs + f0);
        float4 b = *reinterpret_cast<const float4*>(hd + f0);
        float he0 = a.x * b.x, he1 = a.y * b.y, he2 = a.z * b.z, he3 = a.w * b.w;
        const float* w0 = W1 + (size_t)(f0 + 0) * HIDDEN;
        const float* w1 = W1 + (size_t)(f0 + 1) * HIDDEN;
        const float* w2 = W1 + (size_t)(f0 + 2) * HIDDEN;
        const float* w3 = W1 + (size_t)(f0 + 3) * HIDDEN;
#pragma unroll
        for (int j = 0; j < HIDDEN; ++j) {
            float acc = hidden[j];
            acc = fmaf(he0, w0[j], acc);
            acc = fmaf(he1, w1[j], acc);
            acc = fmaf(he2, w2[j], acc);
            acc = fmaf(he3, w3[j], acc);
            hidden[j] = acc;
        }
    }

    float score = b2[0];
#pragma unroll
    for (int j = 0; j < HIDDEN; ++j) {
        float r = hidden[j] > 0.0f ? hidden[j] : 0.0f;
        score = fmaf(r, W2[j], score);
    }
    out[e] = score;
}

extern "C" void kernel_launch(void* const* d_in, const int* in_sizes, int n_in,
                              void* d_out, int out_size, void* d_ws, size_t ws_size,
                              hipStream_t stream) {
    const float* h   = (const float*)d_in[0];
    const int*   src = (const int*)  d_in[1];
    const int*   dst = (const int*)  d_in[2];
    const float* W1  = (const float*)d_in[3];
    const float* b1  = (const float*)d_in[4];
    const float* W2  = (const float*)d_in[5];
    const float* b2  = (const float*)d_in[6];
    float* out = (float*)d_out;

    int n_node_feats = in_sizes[0];            // N * 128
    int n_edges = in_sizes[1];
    int n_nodes = n_node_feats / H_FEATS;
    int nbuck = (n_nodes + (1 << BUCKET_SHIFT) - 1) >> BUCKET_SHIFT;

    const int block = 256;
    int egrid  = (n_edges + block - 1) / block;          // MLP grid (256 edges/block)
    int sgrid  = (n_edges + SORT_EPB - 1) / SORT_EPB;    // sort-pass grid

    // ws layout (256B aligned)
    size_t hh_bytes  = (size_t)n_node_feats * sizeof(__half);
    size_t off_w1t   = (hh_bytes + 255) & ~(size_t)255;
    size_t off_spair = (off_w1t + (size_t)H_FEATS * HIDDEN * 2 + 255) & ~(size_t)255;
    size_t off_seid  = off_spair + (size_t)n_edges * 8;
    size_t off_bh    = off_seid + (size_t)n_edges * 4;
    size_t off_rsum  = off_bh + (size_t)nbuck * sgrid * 4;
    size_t off_base  = off_rsum + (size_t)MAX_BUCKETS * 4;
    size_t need_full = off_base + (size_t)MAX_BUCKETS * 4;

    if (ws_size >= need_full && nbuck <= MAX_BUCKETS) {
        char* ws = (char*)d_ws;
        __half* hh     = (__half*)ws;
        __half* w1t    = (__half*)(ws + off_w1t);
        int2*   spair  = (int2*)(ws + off_spair);
        int*    seid   = (int*)(ws + off_seid);
        int*    blockhist = (int*)(ws + off_bh);
        int*    rowsum = (int*)(ws + off_rsum);
        int*    base   = (int*)(ws + off_base);

        int n8 = n_node_feats / 8;
        convert_h_kernel<<<(n8 + block - 1) / block, block, 0, stream>>>(h, hh, n8);
        convert_w_kernel<<<(H_FEATS * HIDDEN + block - 1) / block, block, 0, stream>>>(W1, w1t);
        hist_kernel<<<sgrid, block, 0, stream>>>(src, blockhist, n_edges, nbuck, sgrid);
        scan_rows_kernel<<<nbuck, block, 0, stream>>>(blockhist, rowsum, sgrid);
        scan_base_kernel<<<1, MAX_BUCKETS, 0, stream>>>(rowsum, base, nbuck);
        scatter_kernel<<<sgrid, block, 0, stream>>>(src, dst, blockhist, base,
                                                    spair, seid,
                                                    n_edges, nbuck, sgrid);
        edge_mlp_mfma_kernel<<<egrid, block, 0, stream>>>(hh, w1t, spair, seid,
                                                          b1, W2, b2, out,
                                                          n_edges, egrid);
    } else if (ws_size >= hh_bytes) {
        __half* hh = (__half*)d_ws;
        int n8 = n_node_feats / 8;
        convert_h_kernel<<<(n8 + block - 1) / block, block, 0, stream>>>(h, hh, n8);
        edge_mlp_fp16_kernel<<<egrid, block, 0, stream>>>(hh, src, dst,
                                                          W1, b1, W2, b2, out, n_edges);
    } else {
        edge_mlp_kernel<<<egrid, block, 0, stream>>>(h, src, dst,
                                                     W1, b1, W2, b2, out, n_edges);
    }
}

// Round 7
// 175.853 us; speedup vs baseline: 5.4248x; 1.0706x over previous
//
#include <hip/hip_runtime.h>
#include <hip/hip_bf16.h>
#include <hip/hip_fp16.h>

#define H_FEATS 128
#define HIDDEN  32
#define BUCKET_SHIFT 9            // 512 nodes/bucket = 256KB fp16 window
#define MAX_BUCKETS 1024
#define SORT_EPB 4096             // edges per block in sort passes

typedef _Float16 f16x8 __attribute__((ext_vector_type(8)));
typedef float    f32x4 __attribute__((ext_vector_type(4)));

union H8 { uint4 u; __half2 h2[4]; };
union U16 { uint4 u; f16x8 h; };

// ---- Pass 1a: h (fp32) -> fp16 rows in ws ----
__global__ __launch_bounds__(256) void convert_h_kernel(
    const float* __restrict__ h, __half* __restrict__ hh, int n8)
{
    int i = blockIdx.x * blockDim.x + threadIdx.x;
    if (i >= n8) return;
    const float4* s = reinterpret_cast<const float4*>(h) + (size_t)i * 2;
    float4 a = s[0], b = s[1];
    H8 r;
    r.h2[0] = __floats2half2_rn(a.x, a.y);
    r.h2[1] = __floats2half2_rn(a.z, a.w);
    r.h2[2] = __floats2half2_rn(b.x, b.y);
    r.h2[3] = __floats2half2_rn(b.z, b.w);
    reinterpret_cast<uint4*>(hh)[i] = r.u;
}

// ---- Pass 1b: W1[128][32] fp32 -> W1T[32][128] fp16 ----
__global__ __launch_bounds__(256) void convert_w_kernel(
    const float* __restrict__ W1, __half* __restrict__ w1t)
{
    int t = blockIdx.x * 256 + threadIdx.x;
    if (t >= H_FEATS * HIDDEN) return;
    int k = t >> 5, n = t & 31;
    w1t[(size_t)n * H_FEATS + k] = __float2half(W1[t]);
}

// ---- Sort pass A: per-block LDS histogram -> blockhist[bucket][block] ----
__global__ __launch_bounds__(256) void hist_kernel(
    const int* __restrict__ src, int* __restrict__ blockhist,
    int n_edges, int nbuck, int nblocks)
{
    __shared__ int lh[MAX_BUCKETS];
    int tid = threadIdx.x;
    for (int i = tid; i < nbuck; i += 256) lh[i] = 0;
    __syncthreads();
    int ebase = blockIdx.x * SORT_EPB;
#pragma unroll
    for (int k = 0; k < SORT_EPB / 256; ++k) {
        int e = ebase + k * 256 + tid;
        if (e < n_edges) atomicAdd(&lh[src[e] >> BUCKET_SHIFT], 1);  // LDS atomic
    }
    __syncthreads();
    for (int i = tid; i < nbuck; i += 256)
        blockhist[(size_t)i * nblocks + blockIdx.x] = lh[i];
}

// ---- Sort pass B1: exclusive scan each bucket-row across blocks ----
__global__ __launch_bounds__(256) void scan_rows_kernel(
    int* __restrict__ blockhist, int* __restrict__ rowsum, int nblocks)
{
    __shared__ int tmp[256];
    int row = blockIdx.x;
    int tid = threadIdx.x;
    size_t rowbase = (size_t)row * nblocks;
    int carry = 0;
    for (int c = 0; c < nblocks; c += 256) {
        int idx = c + tid;
        int v = (idx < nblocks) ? blockhist[rowbase + idx] : 0;
        tmp[tid] = v;
        __syncthreads();
#pragma unroll
        for (int d = 1; d < 256; d <<= 1) {
            int t = (tid >= d) ? tmp[tid - d] : 0;
            __syncthreads();
            tmp[tid] += t;
            __syncthreads();
        }
        int incl = tmp[tid];
        if (idx < nblocks) blockhist[rowbase + idx] = carry + incl - v;
        carry += tmp[255];
        __syncthreads();
    }
    if (tid == 0) rowsum[row] = carry;
}

// ---- Sort pass B2: exclusive scan of bucket totals -> base ----
__global__ __launch_bounds__(MAX_BUCKETS) void scan_base_kernel(
    const int* __restrict__ rowsum, int* __restrict__ base, int nbuck)
{
    __shared__ int tmp[MAX_BUCKETS];
    int tid = threadIdx.x;
    int v = (tid < nbuck) ? rowsum[tid] : 0;
    tmp[tid] = v;
    __syncthreads();
#pragma unroll
    for (int d = 1; d < MAX_BUCKETS; d <<= 1) {
        int t = (tid >= d) ? tmp[tid - d] : 0;
        __syncthreads();
        tmp[tid] += t;
        __syncthreads();
    }
    if (tid < nbuck) base[tid] = tmp[tid] - v;
}

// ---- Sort pass C: place edges via LDS cursors (no global atomics) ----
__global__ __launch_bounds__(256) void scatter_kernel(
    const int* __restrict__ src, const int* __restrict__ dst,
    const int* __restrict__ blockhist, const int* __restrict__ base,
    int2* __restrict__ spair, int* __restrict__ seid,
    int n_edges, int nbuck, int nblocks)
{
    __shared__ int lcur[MAX_BUCKETS];
    int tid = threadIdx.x;
    for (int i = tid; i < nbuck; i += 256)
        lcur[i] = base[i] + blockhist[(size_t)i * nblocks + blockIdx.x];
    __syncthreads();
    int ebase = blockIdx.x * SORT_EPB;
#pragma unroll
    for (int k = 0; k < SORT_EPB / 256; ++k) {
        int e = ebase + k * 256 + tid;
        if (e < n_edges) {
            int s = src[e];
            int p = atomicAdd(&lcur[s >> BUCKET_SHIFT], 1);   // LDS atomic
            spair[p] = make_int2(s, dst[e]);
            seid[p] = e;
        }
    }
}

// ---- MFMA MLP over sorted edges (operand-swapped: D = W1T-tile @ he^T) ----
// Per wave: 4 groups of 16 edges. For each group:
//   A = w1frag (16 hidden x 32 k slice of W1T)  [held in regs all loop]
//   B = he^T   (32 k x 16 edges) — lane (m,kq) loads edge(t0+m) cols kq*8+..
//   D[16 hidden x 16 edges]: col=lane&15=edge, row=(lane>>4)*4+r=hidden
// Epilogue: each lane owns 8 hidden values of ONE edge -> 8 fma+relu local,
// then 2 shfl_xor (16,32) to sum the 4 kq groups; lanes kq==0 write.
// Fragment layout family ref-verified (learn_hip m89/m92/m93) and this exact
// A/B assignment passed refcheck in round 6 (only intrinsic arg order swaps).
__global__ __launch_bounds__(256, 3) void edge_mlp_mfma_kernel(
    const __half* __restrict__ hh,
    const __half* __restrict__ w1t,    // [32][128] fp16
    const int2*  __restrict__ spair,   // sorted (src,dst)
    const int*   __restrict__ seid,    // sorted -> original edge id
    const float* __restrict__ b1,
    const float* __restrict__ W2,
    const float* __restrict__ b2,
    float*       __restrict__ out,
    int n_edges, int nblocks)
{
    // Bijective XCD chunking: contiguous sorted range per XCD -> src rows L2-hit.
    int bid = blockIdx.x;
    int q8 = nblocks >> 3, r8 = nblocks & 7;
    int xcd = bid & 7, idx = bid >> 3;
    int chunk = (xcd < r8) ? (xcd * (q8 + 1) + idx)
                           : (r8 * (q8 + 1) + (xcd - r8) * q8 + idx);
    int tile = chunk * 256;

    int lane = (int)(threadIdx.x & 63);
    int wv   = (int)(threadIdx.x >> 6);
    int m    = lane & 15;
    int kq   = lane >> 4;

    // A fragments: w1frag[nt][s] = W1T rows (hidden) 16*nt+m, k = 32*s+kq*8+[0..8)
    f16x8 w1frag[2][4];
#pragma unroll
    for (int nt = 0; nt < 2; ++nt)
#pragma unroll
        for (int s = 0; s < 4; ++s) {
            U16 t;
            t.u = *reinterpret_cast<const uint4*>(
                w1t + (size_t)(nt * 16 + m) * H_FEATS + s * 32 + kq * 8);
            w1frag[nt][s] = t.h;
        }

    // Per-lane bias/W2 slices: hidden j = kq*4+r (acc0) and 16+kq*4+r (acc1).
    float4 b1lo = *reinterpret_cast<const float4*>(b1 + kq * 4);
    float4 b1hi = *reinterpret_cast<const float4*>(b1 + 16 + kq * 4);
    float4 w2lo = *reinterpret_cast<const float4*>(W2 + kq * 4);
    float4 w2hi = *reinterpret_cast<const float4*>(W2 + 16 + kq * 4);
    float b2f = b2[0];

    int base = tile + wv * 64;
#pragma unroll
    for (int g = 0; g < 4; ++g) {
        int eidx = base + g * 16 + m;
        int ecl  = eidx < n_edges ? eidx : n_edges - 1;
        int2 sp  = spair[ecl];
        const __half* hs = hh + (size_t)sp.x * H_FEATS;
        const __half* hd = hh + (size_t)sp.y * H_FEATS;

        // Batch-issue all 8 gather loads for this group (ILP), then MFMA.
        U16 a[4], b[4];
#pragma unroll
        for (int s = 0; s < 4; ++s) {
            a[s].u = *reinterpret_cast<const uint4*>(hs + s * 32 + kq * 8);
            b[s].u = *reinterpret_cast<const uint4*>(hd + s * 32 + kq * 8);
        }

        f32x4 acc0 = {0.f, 0.f, 0.f, 0.f};
        f32x4 acc1 = {0.f, 0.f, 0.f, 0.f};
#pragma unroll
        for (int s = 0; s < 4; ++s) {
            f16x8 he = a[s].h * b[s].h;
            acc0 = __builtin_amdgcn_mfma_f32_16x16x32_f16(w1frag[0][s], he, acc0, 0, 0, 0);
            acc1 = __builtin_amdgcn_mfma_f32_16x16x32_f16(w1frag[1][s], he, acc1, 0, 0, 0);
        }

        float p = 0.f;
        float* b1lop = reinterpret_cast<float*>(&b1lo);
        float* b1hip = reinterpret_cast<float*>(&b1hi);
        float* w2lop = reinterpret_cast<float*>(&w2lo);
        float* w2hip = reinterpret_cast<float*>(&w2hi);
#pragma unroll
        for (int r = 0; r < 4; ++r) {
            float h0 = acc0[r] + b1lop[r]; h0 = h0 > 0.f ? h0 : 0.f;
            float h1 = acc1[r] + b1hip[r]; h1 = h1 > 0.f ? h1 : 0.f;
            p = fmaf(h0, w2lop[r], p);
            p = fmaf(h1, w2hip[r], p);
        }
        p += __shfl_xor(p, 16, 64);
        p += __shfl_xor(p, 32, 64);
        if (kq == 0 && eidx < n_edges) out[seid[eidx]] = p + b2f;
    }
}

// ---- Fallback: unsorted fp16 scalar path ----
__global__ __launch_bounds__(256) void edge_mlp_fp16_kernel(
    const __half* __restrict__ hh,
    const int*   __restrict__ src,
    const int*   __restrict__ dst,
    const float* __restrict__ W1,
    const float* __restrict__ b1,
    const float* __restrict__ W2,
    const float* __restrict__ b2,
    float*       __restrict__ out,
    int n_edges)
{
    int e = blockIdx.x * blockDim.x + threadIdx.x;
    if (e >= n_edges) return;

    const __half* hs = hh + (size_t)src[e] * H_FEATS;
    const __half* hd = hh + (size_t)dst[e] * H_FEATS;

    float hidden[HIDDEN];
#pragma unroll
    for (int j = 0; j < HIDDEN; ++j) hidden[j] = b1[j];

#pragma unroll 2
    for (int f0 = 0; f0 < H_FEATS; f0 += 8) {
        H8 A, B;
        A.u = *reinterpret_cast<const uint4*>(hs + f0);
        B.u = *reinterpret_cast<const uint4*>(hd + f0);
        float he[8];
#pragma unroll
        for (int k = 0; k < 4; ++k) {
            float2 a = __half22float2(A.h2[k]);
            float2 b = __half22float2(B.h2[k]);
            he[2 * k]     = a.x * b.x;
            he[2 * k + 1] = a.y * b.y;
        }
        const float* w = W1 + (size_t)f0 * HIDDEN;
#pragma unroll
        for (int j = 0; j < HIDDEN; ++j) {
            float acc = hidden[j];
#pragma unroll
            for (int k = 0; k < 8; ++k)
                acc = fmaf(he[k], w[(size_t)k * HIDDEN + j], acc);
            hidden[j] = acc;
        }
    }

    float score = b2[0];
#pragma unroll
    for (int j = 0; j < HIDDEN; ++j) {
        float r = hidden[j] > 0.0f ? hidden[j] : 0.0f;
        score = fmaf(r, W2[j], score);
    }
    out[e] = score;
}

// ---- Fallback: fp32 path (tiny ws) ----
__global__ __launch_bounds__(256) void edge_mlp_kernel(
    const float* __restrict__ h,
    const int*   __restrict__ src,
    const int*   __restrict__ dst,
    const float* __restrict__ W1,
    const float* __restrict__ b1,
    const float* __restrict__ W2,
    const float* __restrict__ b2,
    float*       __restrict__ out,
    int n_edges)
{
    int e = blockIdx.x * blockDim.x + threadIdx.x;
    if (e >= n_edges) return;

    const float* hs = h + (size_t)src[e] * H_FEATS;
    const float* hd = h + (size_t)dst[e] * H_FEATS;

    float hidden[HIDDEN];
#pragma unroll
    for (int j = 0; j < HIDDEN; ++j) hidden[j] = b1[j];

#pragma unroll 4
    for (int f0 = 0; f0 < H_FEATS; f0 += 4) {
        float4 a = *reinterpret_cast<const float4*>(hs + f0);
        float4 b = *reinterpret_cast<const float4*>(hd + f0);
        float he0 = a.x * b.x, he1 = a.y * b.y, he2 = a.z * b.z, he3 = a.w * b.w;
        const float* w0 = W1 + (size_t)(f0 + 0) * HIDDEN;
        const float* w1 = W1 + (size_t)(f0 + 1) * HIDDEN;
        const float* w2 = W1 + (size_t)(f0 + 2) * HIDDEN;
        const float* w3 = W1 + (size_t)(f0 + 3) * HIDDEN;
#pragma unroll
        for (int j = 0; j < HIDDEN; ++j) {
            float acc = hidden[j];
            acc = fmaf(he0, w0[j], acc);
            acc = fmaf(he1, w1[j], acc);
            acc = fmaf(he2, w2[j], acc);
            acc = fmaf(he3, w3[j], acc);
            hidden[j] = acc;
        }
    }

    float score = b2[0];
#pragma unroll
    for (int j = 0; j < HIDDEN; ++j) {
        float r = hidden[j] > 0.0f ? hidden[j] : 0.0f;
        score = fmaf(r, W2[j], score);
    }
    out[e] = score;
}

extern "C" void kernel_launch(void* const* d_in, const int* in_sizes, int n_in,
                              void* d_out, int out_size, void* d_ws, size_t ws_size,
                              hipStream_t stream) {
    const float* h   = (const float*)d_in[0];
    const int*   src = (const int*)  d_in[1];
    const int*   dst = (const int*)  d_in[2];
    const float* W1  = (const float*)d_in[3];
    const float* b1  = (const float*)d_in[4];
    const float* W2  = (const float*)d_in[5];
    const float* b2  = (const float*)d_in[6];
    float* out = (float*)d_out;

    int n_node_feats = in_sizes[0];            // N * 128
    int n_edges = in_sizes[1];
    int n_nodes = n_node_feats / H_FEATS;
    int nbuck = (n_nodes + (1 << BUCKET_SHIFT) - 1) >> BUCKET_SHIFT;

    const int block = 256;
    int egrid  = (n_edges + block - 1) / block;          // MLP grid (256 edges/block)
    int sgrid  = (n_edges + SORT_EPB - 1) / SORT_EPB;    // sort-pass grid

    // ws layout (256B aligned)
    size_t hh_bytes  = (size_t)n_node_feats * sizeof(__half);
    size_t off_w1t   = (hh_bytes + 255) & ~(size_t)255;
    size_t off_spair = (off_w1t + (size_t)H_FEATS * HIDDEN * 2 + 255) & ~(size_t)255;
    size_t off_seid  = off_spair + (size_t)n_edges * 8;
    size_t off_bh    = off_seid + (size_t)n_edges * 4;
    size_t off_rsum  = off_bh + (size_t)nbuck * sgrid * 4;
    size_t off_base  = off_rsum + (size_t)MAX_BUCKETS * 4;
    size_t need_full = off_base + (size_t)MAX_BUCKETS * 4;

    if (ws_size >= need_full && nbuck <= MAX_BUCKETS) {
        char* ws = (char*)d_ws;
        __half* hh     = (__half*)ws;
        __half* w1t    = (__half*)(ws + off_w1t);
        int2*   spair  = (int2*)(ws + off_spair);
        int*    seid   = (int*)(ws + off_seid);
        int*    blockhist = (int*)(ws + off_bh);
        int*    rowsum = (int*)(ws + off_rsum);
        int*    base   = (int*)(ws + off_base);

        int n8 = n_node_feats / 8;
        convert_h_kernel<<<(n8 + block - 1) / block, block, 0, stream>>>(h, hh, n8);
        convert_w_kernel<<<(H_FEATS * HIDDEN + block - 1) / block, block, 0, stream>>>(W1, w1t);
        hist_kernel<<<sgrid, block, 0, stream>>>(src, blockhist, n_edges, nbuck, sgrid);
        scan_rows_kernel<<<nbuck, block, 0, stream>>>(blockhist, rowsum, sgrid);
        scan_base_kernel<<<1, MAX_BUCKETS, 0, stream>>>(rowsum, base, nbuck);
        scatter_kernel<<<sgrid, block, 0, stream>>>(src, dst, blockhist, base,
                                                    spair, seid,
                                                    n_edges, nbuck, sgrid);
        edge_mlp_mfma_kernel<<<egrid, block, 0, stream>>>(hh, w1t, spair, seid,
                                                          b1, W2, b2, out,
                                                          n_edges, egrid);
    } else if (ws_size >= hh_bytes) {
        __half* hh = (__half*)d_ws;
        int n8 = n_node_feats / 8;
        convert_h_kernel<<<(n8 + block - 1) / block, block, 0, stream>>>(h, hh, n8);
        edge_mlp_fp16_kernel<<<egrid, block, 0, stream>>>(hh, src, dst,
                                                          W1, b1, W2, b2, out, n_edges);
    } else {
        edge_mlp_kernel<<<egrid, block, 0, stream>>>(h, src, dst,
                                                     W1, b1, W2, b2, out, n_edges);
    }
}

// Round 9
// 174.600 us; speedup vs baseline: 5.4637x; 1.0072x over previous
//
#include <hip/hip_runtime.h>
#include <hip/hip_bf16.h>
#include <hip/hip_fp16.h>

#define H_FEATS 128
#define HIDDEN  32
#define BUCKET_SHIFT 9            // 512 nodes/bucket = 256KB fp16 window
#define MAX_BUCKETS 1024
#define SORT_EPB 4096             // edges per block in sort passes

typedef _Float16 f16x8 __attribute__((ext_vector_type(8)));
typedef float    f32x4 __attribute__((ext_vector_type(4)));

union H8 { uint4 u; __half2 h2[4]; };
union U16 { uint4 u; f16x8 h; };

// ---- Pass 1a: h (fp32) -> fp16 rows in ws ----
__global__ __launch_bounds__(256) void convert_h_kernel(
    const float* __restrict__ h, __half* __restrict__ hh, int n8)
{
    int i = blockIdx.x * blockDim.x + threadIdx.x;
    if (i >= n8) return;
    const float4* s = reinterpret_cast<const float4*>(h) + (size_t)i * 2;
    float4 a = s[0], b = s[1];
    H8 r;
    r.h2[0] = __floats2half2_rn(a.x, a.y);
    r.h2[1] = __floats2half2_rn(a.z, a.w);
    r.h2[2] = __floats2half2_rn(b.x, b.y);
    r.h2[3] = __floats2half2_rn(b.z, b.w);
    reinterpret_cast<uint4*>(hh)[i] = r.u;
}

// ---- Pass 1b: W1[128][32] fp32 -> W1T[32][128] fp16 ----
__global__ __launch_bounds__(256) void convert_w_kernel(
    const float* __restrict__ W1, __half* __restrict__ w1t)
{
    int t = blockIdx.x * 256 + threadIdx.x;
    if (t >= H_FEATS * HIDDEN) return;
    int k = t >> 5, n = t & 31;
    w1t[(size_t)n * H_FEATS + k] = __float2half(W1[t]);
}

// ---- Sort pass A: per-block LDS histogram -> blockhist[bucket][block] ----
__global__ __launch_bounds__(256) void hist_kernel(
    const int* __restrict__ src, int* __restrict__ blockhist,
    int n_edges, int nbuck, int nblocks)
{
    __shared__ int lh[MAX_BUCKETS];
    int tid = threadIdx.x;
    for (int i = tid; i < nbuck; i += 256) lh[i] = 0;
    __syncthreads();
    int ebase = blockIdx.x * SORT_EPB;
#pragma unroll
    for (int k = 0; k < SORT_EPB / 256; ++k) {
        int e = ebase + k * 256 + tid;
        if (e < n_edges) atomicAdd(&lh[src[e] >> BUCKET_SHIFT], 1);  // LDS atomic
    }
    __syncthreads();
    for (int i = tid; i < nbuck; i += 256)
        blockhist[(size_t)i * nblocks + blockIdx.x] = lh[i];
}

// ---- Sort pass B1: exclusive scan each bucket-row across blocks ----
__global__ __launch_bounds__(256) void scan_rows_kernel(
    int* __restrict__ blockhist, int* __restrict__ rowsum, int nblocks)
{
    __shared__ int tmp[256];
    int row = blockIdx.x;
    int tid = threadIdx.x;
    size_t rowbase = (size_t)row * nblocks;
    int carry = 0;
    for (int c = 0; c < nblocks; c += 256) {
        int idx = c + tid;
        int v = (idx < nblocks) ? blockhist[rowbase + idx] : 0;
        tmp[tid] = v;
        __syncthreads();
#pragma unroll
        for (int d = 1; d < 256; d <<= 1) {
            int t = (tid >= d) ? tmp[tid - d] : 0;
            __syncthreads();
            tmp[tid] += t;
            __syncthreads();
        }
        int incl = tmp[tid];
        if (idx < nblocks) blockhist[rowbase + idx] = carry + incl - v;
        carry += tmp[255];
        __syncthreads();
    }
    if (tid == 0) rowsum[row] = carry;
}

// ---- Sort pass B2: exclusive scan of bucket totals -> base ----
__global__ __launch_bounds__(MAX_BUCKETS) void scan_base_kernel(
    const int* __restrict__ rowsum, int* __restrict__ base, int nbuck)
{
    __shared__ int tmp[MAX_BUCKETS];
    int tid = threadIdx.x;
    int v = (tid < nbuck) ? rowsum[tid] : 0;
    tmp[tid] = v;
    __syncthreads();
#pragma unroll
    for (int d = 1; d < MAX_BUCKETS; d <<= 1) {
        int t = (tid >= d) ? tmp[tid - d] : 0;
        __syncthreads();
        tmp[tid] += t;
        __syncthreads();
    }
    if (tid < nbuck) base[tid] = tmp[tid] - v;
}

// ---- Sort pass C: place edges via LDS cursors (no global atomics) ----
__global__ __launch_bounds__(256) void scatter_kernel(
    const int* __restrict__ src, const int* __restrict__ dst,
    const int* __restrict__ blockhist, const int* __restrict__ base,
    int2* __restrict__ spair, int* __restrict__ seid,
    int n_edges, int nbuck, int nblocks)
{
    __shared__ int lcur[MAX_BUCKETS];
    int tid = threadIdx.x;
    for (int i = tid; i < nbuck; i += 256)
        lcur[i] = base[i] + blockhist[(size_t)i * nblocks + blockIdx.x];
    __syncthreads();
    int ebase = blockIdx.x * SORT_EPB;
#pragma unroll
    for (int k = 0; k < SORT_EPB / 256; ++k) {
        int e = ebase + k * 256 + tid;
        if (e < n_edges) {
            int s = src[e];
            int p = atomicAdd(&lcur[s >> BUCKET_SHIFT], 1);   // LDS atomic
            spair[p] = make_int2(s, dst[e]);
            seid[p] = e;
        }
    }
}

// ---- MFMA MLP helpers (arrays with compile-time indices only) ----
__device__ __forceinline__ void issue_g(
    const __half* __restrict__ hh, int2 sp, int koff, U16 (&A)[4], U16 (&B)[4])
{
    const __half* hs = hh + (size_t)sp.x * H_FEATS;
    const __half* hd = hh + (size_t)sp.y * H_FEATS;
#pragma unroll
    for (int s = 0; s < 4; ++s) {
        A[s].u = *reinterpret_cast<const uint4*>(hs + s * 32 + koff);
        B[s].u = *reinterpret_cast<const uint4*>(hd + s * 32 + koff);
    }
}

__device__ __forceinline__ void compute_g(
    U16 (&A)[4], U16 (&B)[4], const f16x8 (&w1frag)[2][4],
    const float* b1lop, const float* b1hip, const float* w2lop, const float* w2hip,
    float b2f, int kq, int sid, bool eok, float* __restrict__ out)
{
    f32x4 acc0 = {0.f, 0.f, 0.f, 0.f};
    f32x4 acc1 = {0.f, 0.f, 0.f, 0.f};
#pragma unroll
    for (int s = 0; s < 4; ++s) {
        f16x8 he = A[s].h * B[s].h;
        acc0 = __builtin_amdgcn_mfma_f32_16x16x32_f16(w1frag[0][s], he, acc0, 0, 0, 0);
        acc1 = __builtin_amdgcn_mfma_f32_16x16x32_f16(w1frag[1][s], he, acc1, 0, 0, 0);
    }
    float p = 0.f;
#pragma unroll
    for (int r = 0; r < 4; ++r) {
        float h0 = acc0[r] + b1lop[r]; h0 = h0 > 0.f ? h0 : 0.f;
        float h1 = acc1[r] + b1hip[r]; h1 = h1 > 0.f ? h1 : 0.f;
        p = fmaf(h0, w2lop[r], p);
        p = fmaf(h1, w2hip[r], p);
    }
    p += __shfl_xor(p, 16, 64);
    p += __shfl_xor(p, 32, 64);
    if (kq == 0 && eok) out[sid] = p + b2f;
}

// ---- MFMA MLP over sorted edges (operand-swapped: D = W1T-tile @ he^T) ----
// Explicit 2-deep software pipeline over 4 groups of 16 edges: two named
// buffer arrays (static indexing), loads for group g+1 issued before compute
// of group g so 8-16 uint4 gathers stay in flight per wave.
// Frag layouts ref-verified (learn_hip m89/m92/m93) + round-6/7 refcheck.
__global__ __launch_bounds__(256, 3) void edge_mlp_mfma_kernel(
    const __half* __restrict__ hh,
    const __half* __restrict__ w1t,    // [32][128] fp16
    const int2*  __restrict__ spair,   // sorted (src,dst)
    const int*   __restrict__ seid,    // sorted -> original edge id
    const float* __restrict__ b1,
    const float* __restrict__ W2,
    const float* __restrict__ b2,
    float*       __restrict__ out,
    int n_edges, int nblocks)
{
    // Bijective XCD chunking: contiguous sorted range per XCD -> src rows L2-hit.
    int bid = blockIdx.x;
    int q8 = nblocks >> 3, r8 = nblocks & 7;
    int xcd = bid & 7, idx = bid >> 3;
    int chunk = (xcd < r8) ? (xcd * (q8 + 1) + idx)
                           : (r8 * (q8 + 1) + (xcd - r8) * q8 + idx);
    int tile = chunk * 256;

    int lane = (int)(threadIdx.x & 63);
    int wv   = (int)(threadIdx.x >> 6);
    int m    = lane & 15;
    int kq   = lane >> 4;
    int koff = kq * 8;

    // A fragments: w1frag[nt][s] = W1T rows (hidden) 16*nt+m, k = 32*s+kq*8+[0..8)
    f16x8 w1frag[2][4];
#pragma unroll
    for (int nt = 0; nt < 2; ++nt)
#pragma unroll
        for (int s = 0; s < 4; ++s) {
            U16 t;
            t.u = *reinterpret_cast<const uint4*>(
                w1t + (size_t)(nt * 16 + m) * H_FEATS + s * 32 + koff);
            w1frag[nt][s] = t.h;
        }

    // Per-lane bias/W2 slices: hidden j = kq*4+r (acc0) and 16+kq*4+r (acc1).
    float4 b1lo = *reinterpret_cast<const float4*>(b1 + kq * 4);
    float4 b1hi = *reinterpret_cast<const float4*>(b1 + 16 + kq * 4);
    float4 w2lo = *reinterpret_cast<const float4*>(W2 + kq * 4);
    float4 w2hi = *reinterpret_cast<const float4*>(W2 + 16 + kq * 4);
    const float* b1lop = reinterpret_cast<const float*>(&b1lo);
    const float* b1hip = reinterpret_cast<const float*>(&b1hi);
    const float* w2lop = reinterpret_cast<const float*>(&w2lo);
    const float* w2hip = reinterpret_cast<const float*>(&w2hi);
    float b2f = b2[0];

    int base = tile + wv * 64;

    // Preload edge metadata for all 4 groups.
    int e0 = base + m,      e1 = base + 16 + m;
    int e2 = base + 32 + m, e3 = base + 48 + m;
    bool ok0 = e0 < n_edges, ok1 = e1 < n_edges, ok2 = e2 < n_edges, ok3 = e3 < n_edges;
    int2 sp0 = spair[ok0 ? e0 : n_edges - 1];
    int2 sp1 = spair[ok1 ? e1 : n_edges - 1];
    int2 sp2 = spair[ok2 ? e2 : n_edges - 1];
    int2 sp3 = spair[ok3 ? e3 : n_edges - 1];
    int sid0 = seid[ok0 ? e0 : n_edges - 1];
    int sid1 = seid[ok1 ? e1 : n_edges - 1];
    int sid2 = seid[ok2 ? e2 : n_edges - 1];
    int sid3 = seid[ok3 ? e3 : n_edges - 1];

    // Two named buffer sets (16 uint4 = 64 VGPRs of gather data in flight).
    U16 xA[4], xB[4];
    U16 yA[4], yB[4];

    issue_g(hh, sp0, koff, xA, xB);
    issue_g(hh, sp1, koff, yA, yB);
    compute_g(xA, xB, w1frag, b1lop, b1hip, w2lop, w2hip, b2f, kq, sid0, ok0, out);
    issue_g(hh, sp2, koff, xA, xB);
    compute_g(yA, yB, w1frag, b1lop, b1hip, w2lop, w2hip, b2f, kq, sid1, ok1, out);
    issue_g(hh, sp3, koff, yA, yB);
    compute_g(xA, xB, w1frag, b1lop, b1hip, w2lop, w2hip, b2f, kq, sid2, ok2, out);
    compute_g(yA, yB, w1frag, b1lop, b1hip, w2lop, w2hip, b2f, kq, sid3, ok3, out);
}

// ---- Fallback: unsorted fp16 scalar path ----
__global__ __launch_bounds__(256) void edge_mlp_fp16_kernel(
    const __half* __restrict__ hh,
    const int*   __restrict__ src,
    const int*   __restrict__ dst,
    const float* __restrict__ W1,
    const float* __restrict__ b1,
    const float* __restrict__ W2,
    const float* __restrict__ b2,
    float*       __restrict__ out,
    int n_edges)
{
    int e = blockIdx.x * blockDim.x + threadIdx.x;
    if (e >= n_edges) return;

    const __half* hs = hh + (size_t)src[e] * H_FEATS;
    const __half* hd = hh + (size_t)dst[e] * H_FEATS;

    float hidden[HIDDEN];
#pragma unroll
    for (int j = 0; j < HIDDEN; ++j) hidden[j] = b1[j];

#pragma unroll 2
    for (int f0 = 0; f0 < H_FEATS; f0 += 8) {
        H8 A, B;
        A.u = *reinterpret_cast<const uint4*>(hs + f0);
        B.u = *reinterpret_cast<const uint4*>(hd + f0);
        float he[8];
#pragma unroll
        for (int k = 0; k < 4; ++k) {
            float2 a = __half22float2(A.h2[k]);
            float2 b = __half22float2(B.h2[k]);
            he[2 * k]     = a.x * b.x;
            he[2 * k + 1] = a.y * b.y;
        }
        const float* w = W1 + (size_t)f0 * HIDDEN;
#pragma unroll
        for (int j = 0; j < HIDDEN; ++j) {
            float acc = hidden[j];
#pragma unroll
            for (int k = 0; k < 8; ++k)
                acc = fmaf(he[k], w[(size_t)k * HIDDEN + j], acc);
            hidden[j] = acc;
        }
    }

    float score = b2[0];
#pragma unroll
    for (int j = 0; j < HIDDEN; ++j) {
        float r = hidden[j] > 0.0f ? hidden[j] : 0.0f;
        score = fmaf(r, W2[j], score);
    }
    out[e] = score;
}

// ---- Fallback: fp32 path (tiny ws) ----
__global__ __launch_bounds__(256) void edge_mlp_kernel(
    const float* __restrict__ h,
    const int*   __restrict__ src,
    const int*   __restrict__ dst,
    const float* __restrict__ W1,
    const float* __restrict__ b1,
    const float* __restrict__ W2,
    const float* __restrict__ b2,
    float*       __restrict__ out,
    int n_edges)
{
    int e = blockIdx.x * blockDim.x + threadIdx.x;
    if (e >= n_edges) return;

    const float* hs = h + (size_t)src[e] * H_FEATS;
    const float* hd = h + (size_t)dst[e] * H_FEATS;

    float hidden[HIDDEN];
#pragma unroll
    for (int j = 0; j < HIDDEN; ++j) hidden[j] = b1[j];

#pragma unroll 4
    for (int f0 = 0; f0 < H_FEATS; f0 += 4) {
        float4 a = *reinterpret_cast<const float4*>(hs + f0);
        float4 b = *reinterpret_cast<const float4*>(hd + f0);
        float he0 = a.x * b.x, he1 = a.y * b.y, he2 = a.z * b.z, he3 = a.w * b.w;
        const float* w0 = W1 + (size_t)(f0 + 0) * HIDDEN;
        const float* w1 = W1 + (size_t)(f0 + 1) * HIDDEN;
        const float* w2 = W1 + (size_t)(f0 + 2) * HIDDEN;
        const float* w3 = W1 + (size_t)(f0 + 3) * HIDDEN;
#pragma unroll
        for (int j = 0; j < HIDDEN; ++j) {
            float acc = hidden[j];
            acc = fmaf(he0, w0[j], acc);
            acc = fmaf(he1, w1[j], acc);
            acc = fmaf(he2, w2[j], acc);
            acc = fmaf(he3, w3[j], acc);
            hidden[j] = acc;
        }
    }

    float score = b2[0];
#pragma unroll
    for (int j = 0; j < HIDDEN; ++j) {
        float r = hidden[j] > 0.0f ? hidden[j] : 0.0f;
        score = fmaf(r, W2[j], score);
    }
    out[e] = score;
}

extern "C" void kernel_launch(void* const* d_in, const int* in_sizes, int n_in,
                              void* d_out, int out_size, void* d_ws, size_t ws_size,
                              hipStream_t stream) {
    const float* h   = (const float*)d_in[0];
    const int*   src = (const int*)  d_in[1];
    const int*   dst = (const int*)  d_in[2];
    const float* W1  = (const float*)d_in[3];
    const float* b1  = (const float*)d_in[4];
    const float* W2  = (const float*)d_in[5];
    const float* b2  = (const float*)d_in[6];
    float* out = (float*)d_out;

    int n_node_feats = in_sizes[0];            // N * 128
    int n_edges = in_sizes[1];
    int n_nodes = n_node_feats / H_FEATS;
    int nbuck = (n_nodes + (1 << BUCKET_SHIFT) - 1) >> BUCKET_SHIFT;

    const int block = 256;
    int egrid  = (n_edges + block - 1) / block;          // MLP grid (256 edges/block)
    int sgrid  = (n_edges + SORT_EPB - 1) / SORT_EPB;    // sort-pass grid

    // ws layout (256B aligned)
    size_t hh_bytes  = (size_t)n_node_feats * sizeof(__half);
    size_t off_w1t   = (hh_bytes + 255) & ~(size_t)255;
    size_t off_spair = (off_w1t + (size_t)H_FEATS * HIDDEN * 2 + 255) & ~(size_t)255;
    size_t off_seid  = off_spair + (size_t)n_edges * 8;
    size_t off_bh    = off_seid + (size_t)n_edges * 4;
    size_t off_rsum  = off_bh + (size_t)nbuck * sgrid * 4;
    size_t off_base  = off_rsum + (size_t)MAX_BUCKETS * 4;
    size_t need_full = off_base + (size_t)MAX_BUCKETS * 4;

    if (ws_size >= need_full && nbuck <= MAX_BUCKETS) {
        char* ws = (char*)d_ws;
        __half* hh     = (__half*)ws;
        __half* w1t    = (__half*)(ws + off_w1t);
        int2*   spair  = (int2*)(ws + off_spair);
        int*    seid   = (int*)(ws + off_seid);
        int*    blockhist = (int*)(ws + off_bh);
        int*    rowsum = (int*)(ws + off_rsum);
        int*    base   = (int*)(ws + off_base);

        int n8 = n_node_feats / 8;
        convert_h_kernel<<<(n8 + block - 1) / block, block, 0, stream>>>(h, hh, n8);
        convert_w_kernel<<<(H_FEATS * HIDDEN + block - 1) / block, block, 0, stream>>>(W1, w1t);
        hist_kernel<<<sgrid, block, 0, stream>>>(src, blockhist, n_edges, nbuck, sgrid);
        scan_rows_kernel<<<nbuck, block, 0, stream>>>(blockhist, rowsum, sgrid);
        scan_base_kernel<<<1, MAX_BUCKETS, 0, stream>>>(rowsum, base, nbuck);
        scatter_kernel<<<sgrid, block, 0, stream>>>(src, dst, blockhist, base,
                                                    spair, seid,
                                                    n_edges, nbuck, sgrid);
        edge_mlp_mfma_kernel<<<egrid, block, 0, stream>>>(hh, w1t, spair, seid,
                                                          b1, W2, b2, out,
                                                          n_edges, egrid);
    } else if (ws_size >= hh_bytes) {
        __half* hh = (__half*)d_ws;
        int n8 = n_node_feats / 8;
        convert_h_kernel<<<(n8 + block - 1) / block, block, 0, stream>>>(h, hh, n8);
        edge_mlp_fp16_kernel<<<egrid, block, 0, stream>>>(hh, src, dst,
                                                          W1, b1, W2, b2, out, n_edges);
    } else {
        edge_mlp_kernel<<<egrid, block, 0, stream>>>(h, src, dst,
                                                     W1, b1, W2, b2, out, n_edges);
    }
}

// Round 11
// 174.306 us; speedup vs baseline: 5.4730x; 1.0017x over previous
//
#include <hip/hip_runtime.h>
#include <hip/hip_bf16.h>
#include <hip/hip_fp16.h>

#define H_FEATS 128
#define HIDDEN  32
#define BUCKET_SHIFT 9            // 512 nodes/bucket = 256KB fp16 window
#define MAX_BUCKETS 1024
#define SORT_EPB 4096             // edges per block in sort passes

typedef _Float16 f16x8 __attribute__((ext_vector_type(8)));
typedef float    f32x4 __attribute__((ext_vector_type(4)));

union H8 { uint4 u; __half2 h2[4]; };
union U16 { uint4 u; f16x8 h; };

// ---- Pass 1a: h (fp32) -> fp16 rows in ws ----
__global__ __launch_bounds__(256) void convert_h_kernel(
    const float* __restrict__ h, __half* __restrict__ hh, int n8)
{
    int i = blockIdx.x * blockDim.x + threadIdx.x;
    if (i >= n8) return;
    const float4* s = reinterpret_cast<const float4*>(h) + (size_t)i * 2;
    float4 a = s[0], b = s[1];
    H8 r;
    r.h2[0] = __floats2half2_rn(a.x, a.y);
    r.h2[1] = __floats2half2_rn(a.z, a.w);
    r.h2[2] = __floats2half2_rn(b.x, b.y);
    r.h2[3] = __floats2half2_rn(b.z, b.w);
    reinterpret_cast<uint4*>(hh)[i] = r.u;
}

// ---- Pass 1b: W1[128][32] fp32 -> W1T[32][128] fp16 ----
__global__ __launch_bounds__(256) void convert_w_kernel(
    const float* __restrict__ W1, __half* __restrict__ w1t)
{
    int t = blockIdx.x * 256 + threadIdx.x;
    if (t >= H_FEATS * HIDDEN) return;
    int k = t >> 5, n = t & 31;
    w1t[(size_t)n * H_FEATS + k] = __float2half(W1[t]);
}

// ---- Sort pass A: per-block LDS histogram -> blockhist[bucket][block] ----
__global__ __launch_bounds__(256) void hist_kernel(
    const int* __restrict__ src, int* __restrict__ blockhist,
    int n_edges, int nbuck, int nblocks)
{
    __shared__ int lh[MAX_BUCKETS];
    int tid = threadIdx.x;
    for (int i = tid; i < nbuck; i += 256) lh[i] = 0;
    __syncthreads();
    int ebase = blockIdx.x * SORT_EPB;
#pragma unroll
    for (int k = 0; k < SORT_EPB / 256; ++k) {
        int e = ebase + k * 256 + tid;
        if (e < n_edges) atomicAdd(&lh[src[e] >> BUCKET_SHIFT], 1);  // LDS atomic
    }
    __syncthreads();
    for (int i = tid; i < nbuck; i += 256)
        blockhist[(size_t)i * nblocks + blockIdx.x] = lh[i];
}

// ---- Sort pass B1: exclusive scan each bucket-row across blocks ----
__global__ __launch_bounds__(256) void scan_rows_kernel(
    int* __restrict__ blockhist, int* __restrict__ rowsum, int nblocks)
{
    __shared__ int tmp[256];
    int row = blockIdx.x;
    int tid = threadIdx.x;
    size_t rowbase = (size_t)row * nblocks;
    int carry = 0;
    for (int c = 0; c < nblocks; c += 256) {
        int idx = c + tid;
        int v = (idx < nblocks) ? blockhist[rowbase + idx] : 0;
        tmp[tid] = v;
        __syncthreads();
#pragma unroll
        for (int d = 1; d < 256; d <<= 1) {
            int t = (tid >= d) ? tmp[tid - d] : 0;
            __syncthreads();
            tmp[tid] += t;
            __syncthreads();
        }
        int incl = tmp[tid];
        if (idx < nblocks) blockhist[rowbase + idx] = carry + incl - v;
        carry += tmp[255];
        __syncthreads();
    }
    if (tid == 0) rowsum[row] = carry;
}

// ---- Sort pass B2: exclusive scan of bucket totals -> base ----
__global__ __launch_bounds__(MAX_BUCKETS) void scan_base_kernel(
    const int* __restrict__ rowsum, int* __restrict__ base, int nbuck)
{
    __shared__ int tmp[MAX_BUCKETS];
    int tid = threadIdx.x;
    int v = (tid < nbuck) ? rowsum[tid] : 0;
    tmp[tid] = v;
    __syncthreads();
#pragma unroll
    for (int d = 1; d < MAX_BUCKETS; d <<= 1) {
        int t = (tid >= d) ? tmp[tid - d] : 0;
        __syncthreads();
        tmp[tid] += t;
        __syncthreads();
    }
    if (tid < nbuck) base[tid] = tmp[tid] - v;
}

// ---- Sort pass C: place edges via LDS cursors (no global atomics) ----
__global__ __launch_bounds__(256) void scatter_kernel(
    const int* __restrict__ src, const int* __restrict__ dst,
    const int* __restrict__ blockhist, const int* __restrict__ base,
    int2* __restrict__ spair, int* __restrict__ seid,
    int n_edges, int nbuck, int nblocks)
{
    __shared__ int lcur[MAX_BUCKETS];
    int tid = threadIdx.x;
    for (int i = tid; i < nbuck; i += 256)
        lcur[i] = base[i] + blockhist[(size_t)i * nblocks + blockIdx.x];
    __syncthreads();
    int ebase = blockIdx.x * SORT_EPB;
#pragma unroll
    for (int k = 0; k < SORT_EPB / 256; ++k) {
        int e = ebase + k * 256 + tid;
        if (e < n_edges) {
            int s = src[e];
            int p = atomicAdd(&lcur[s >> BUCKET_SHIFT], 1);   // LDS atomic
            spair[p] = make_int2(s, dst[e]);
            seid[p] = e;
        }
    }
}

// ---- MFMA MLP helpers (arrays with compile-time indices only) ----
__device__ __forceinline__ void issue_g(
    const __half* __restrict__ hh, int2 sp, int koff, U16 (&A)[4], U16 (&B)[4])
{
    const __half* hs = hh + (size_t)sp.x * H_FEATS;
    const __half* hd = hh + (size_t)sp.y * H_FEATS;
#pragma unroll
    for (int s = 0; s < 4; ++s) {
        A[s].u = *reinterpret_cast<const uint4*>(hs + s * 32 + koff);
        B[s].u = *reinterpret_cast<const uint4*>(hd + s * 32 + koff);
    }
}

__device__ __forceinline__ void compute_g(
    U16 (&A)[4], U16 (&B)[4], const f16x8 (&w1frag)[2][4],
    const float* b1lop, const float* b1hip, const float* w2lop, const float* w2hip,
    float b2f, int kq, int sid, bool eok, float* __restrict__ out)
{
    f32x4 acc0 = {0.f, 0.f, 0.f, 0.f};
    f32x4 acc1 = {0.f, 0.f, 0.f, 0.f};
#pragma unroll
    for (int s = 0; s < 4; ++s) {
        f16x8 he = A[s].h * B[s].h;
        acc0 = __builtin_amdgcn_mfma_f32_16x16x32_f16(w1frag[0][s], he, acc0, 0, 0, 0);
        acc1 = __builtin_amdgcn_mfma_f32_16x16x32_f16(w1frag[1][s], he, acc1, 0, 0, 0);
    }
    float p = 0.f;
#pragma unroll
    for (int r = 0; r < 4; ++r) {
        float h0 = acc0[r] + b1lop[r]; h0 = h0 > 0.f ? h0 : 0.f;
        float h1 = acc1[r] + b1hip[r]; h1 = h1 > 0.f ? h1 : 0.f;
        p = fmaf(h0, w2lop[r], p);
        p = fmaf(h1, w2hip[r], p);
    }
    p += __shfl_xor(p, 16, 64);
    p += __shfl_xor(p, 32, 64);
    if (kq == 0 && eok) out[sid] = p + b2f;
}

// ---- MFMA MLP over sorted edges (operand-swapped: D = W1T-tile @ he^T) ----
// 3-deep software pipeline over 4 groups of 16 edges, with
// __builtin_amdgcn_sched_barrier(0) pinning each stage so the scheduler
// cannot collapse the pipeline to save registers (it did in r7/r9: VGPR=44/64).
__global__ __launch_bounds__(256, 2) void edge_mlp_mfma_kernel(
    const __half* __restrict__ hh,
    const __half* __restrict__ w1t,    // [32][128] fp16
    const int2*  __restrict__ spair,   // sorted (src,dst)
    const int*   __restrict__ seid,    // sorted -> original edge id
    const float* __restrict__ b1,
    const float* __restrict__ W2,
    const float* __restrict__ b2,
    float*       __restrict__ out,
    int n_edges, int nblocks)
{
    // Bijective XCD chunking: contiguous sorted range per XCD -> src rows L2-hit.
    int bid = blockIdx.x;
    int q8 = nblocks >> 3, r8 = nblocks & 7;
    int xcd = bid & 7, idx = bid >> 3;
    int chunk = (xcd < r8) ? (xcd * (q8 + 1) + idx)
                           : (r8 * (q8 + 1) + (xcd - r8) * q8 + idx);
    int tile = chunk * 256;

    int lane = (int)(threadIdx.x & 63);
    int wv   = (int)(threadIdx.x >> 6);
    int m    = lane & 15;
    int kq   = lane >> 4;
    int koff = kq * 8;

    // A fragments: w1frag[nt][s] = W1T rows (hidden) 16*nt+m, k = 32*s+kq*8+[0..8)
    f16x8 w1frag[2][4];
#pragma unroll
    for (int nt = 0; nt < 2; ++nt)
#pragma unroll
        for (int s = 0; s < 4; ++s) {
            U16 t;
            t.u = *reinterpret_cast<const uint4*>(
                w1t + (size_t)(nt * 16 + m) * H_FEATS + s * 32 + koff);
            w1frag[nt][s] = t.h;
        }

    // Per-lane bias/W2 slices: hidden j = kq*4+r (acc0) and 16+kq*4+r (acc1).
    float4 b1lo = *reinterpret_cast<const float4*>(b1 + kq * 4);
    float4 b1hi = *reinterpret_cast<const float4*>(b1 + 16 + kq * 4);
    float4 w2lo = *reinterpret_cast<const float4*>(W2 + kq * 4);
    float4 w2hi = *reinterpret_cast<const float4*>(W2 + 16 + kq * 4);
    const float* b1lop = reinterpret_cast<const float*>(&b1lo);
    const float* b1hip = reinterpret_cast<const float*>(&b1hi);
    const float* w2lop = reinterpret_cast<const float*>(&w2lo);
    const float* w2hip = reinterpret_cast<const float*>(&w2hi);
    float b2f = b2[0];

    int base = tile + wv * 64;

    // Preload edge metadata for all 4 groups.
    int e0 = base + m,      e1 = base + 16 + m;
    int e2 = base + 32 + m, e3 = base + 48 + m;
    bool ok0 = e0 < n_edges, ok1 = e1 < n_edges, ok2 = e2 < n_edges, ok3 = e3 < n_edges;
    int2 sp0 = spair[ok0 ? e0 : n_edges - 1];
    int2 sp1 = spair[ok1 ? e1 : n_edges - 1];
    int2 sp2 = spair[ok2 ? e2 : n_edges - 1];
    int2 sp3 = spair[ok3 ? e3 : n_edges - 1];
    int sid0 = seid[ok0 ? e0 : n_edges - 1];
    int sid1 = seid[ok1 ? e1 : n_edges - 1];
    int sid2 = seid[ok2 ? e2 : n_edges - 1];
    int sid3 = seid[ok3 ? e3 : n_edges - 1];

    // Three named buffer sets (24 uint4 = 96 VGPRs of gather data in flight).
    U16 xA[4], xB[4];
    U16 yA[4], yB[4];
    U16 zA[4], zB[4];

    issue_g(hh, sp0, koff, xA, xB);
    issue_g(hh, sp1, koff, yA, yB);
    issue_g(hh, sp2, koff, zA, zB);
    __builtin_amdgcn_sched_barrier(0);
    compute_g(xA, xB, w1frag, b1lop, b1hip, w2lop, w2hip, b2f, kq, sid0, ok0, out);
    __builtin_amdgcn_sched_barrier(0);
    issue_g(hh, sp3, koff, xA, xB);
    __builtin_amdgcn_sched_barrier(0);
    compute_g(yA, yB, w1frag, b1lop, b1hip, w2lop, w2hip, b2f, kq, sid1, ok1, out);
    __builtin_amdgcn_sched_barrier(0);
    compute_g(zA, zB, w1frag, b1lop, b1hip, w2lop, w2hip, b2f, kq, sid2, ok2, out);
    __builtin_amdgcn_sched_barrier(0);
    compute_g(xA, xB, w1frag, b1lop, b1hip, w2lop, w2hip, b2f, kq, sid3, ok3, out);
}

// ---- Fallback: unsorted fp16 scalar path ----
__global__ __launch_bounds__(256) void edge_mlp_fp16_kernel(
    const __half* __restrict__ hh,
    const int*   __restrict__ src,
    const int*   __restrict__ dst,
    const float* __restrict__ W1,
    const float* __restrict__ b1,
    const float* __restrict__ W2,
    const float* __restrict__ b2,
    float*       __restrict__ out,
    int n_edges)
{
    int e = blockIdx.x * blockDim.x + threadIdx.x;
    if (e >= n_edges) return;

    const __half* hs = hh + (size_t)src[e] * H_FEATS;
    const __half* hd = hh + (size_t)dst[e] * H_FEATS;

    float hidden[HIDDEN];
#pragma unroll
    for (int j = 0; j < HIDDEN; ++j) hidden[j] = b1[j];

#pragma unroll 2
    for (int f0 = 0; f0 < H_FEATS; f0 += 8) {
        H8 A, B;
        A.u = *reinterpret_cast<const uint4*>(hs + f0);
        B.u = *reinterpret_cast<const uint4*>(hd + f0);
        float he[8];
#pragma unroll
        for (int k = 0; k < 4; ++k) {
            float2 a = __half22float2(A.h2[k]);
            float2 b = __half22float2(B.h2[k]);
            he[2 * k]     = a.x * b.x;
            he[2 * k + 1] = a.y * b.y;
        }
        const float* w = W1 + (size_t)f0 * HIDDEN;
#pragma unroll
        for (int j = 0; j < HIDDEN; ++j) {
            float acc = hidden[j];
#pragma unroll
            for (int k = 0; k < 8; ++k)
                acc = fmaf(he[k], w[(size_t)k * HIDDEN + j], acc);
            hidden[j] = acc;
        }
    }

    float score = b2[0];
#pragma unroll
    for (int j = 0; j < HIDDEN; ++j) {
        float r = hidden[j] > 0.0f ? hidden[j] : 0.0f;
        score = fmaf(r, W2[j], score);
    }
    out[e] = score;
}

// ---- Fallback: fp32 path (tiny ws) ----
__global__ __launch_bounds__(256) void edge_mlp_kernel(
    const float* __restrict__ h,
    const int*   __restrict__ src,
    const int*   __restrict__ dst,
    const float* __restrict__ W1,
    const float* __restrict__ b1,
    const float* __restrict__ W2,
    const float* __restrict__ b2,
    float*       __restrict__ out,
    int n_edges)
{
    int e = blockIdx.x * blockDim.x + threadIdx.x;
    if (e >= n_edges) return;

    const float* hs = h + (size_t)src[e] * H_FEATS;
    const float* hd = h + (size_t)dst[e] * H_FEATS;

    float hidden[HIDDEN];
#pragma unroll
    for (int j = 0; j < HIDDEN; ++j) hidden[j] = b1[j];

#pragma unroll 4
    for (int f0 = 0; f0 < H_FEATS; f0 += 4) {
        float4 a = *reinterpret_cast<const float4*>(hs + f0);
        float4 b = *reinterpret_cast<const float4*>(hd + f0);
        float he0 = a.x * b.x, he1 = a.y * b.y, he2 = a.z * b.z, he3 = a.w * b.w;
        const float* w0 = W1 + (size_t)(f0 + 0) * HIDDEN;
        const float* w1 = W1 + (size_t)(f0 + 1) * HIDDEN;
        const float* w2 = W1 + (size_t)(f0 + 2) * HIDDEN;
        const float* w3 = W1 + (size_t)(f0 + 3) * HIDDEN;
#pragma unroll
        for (int j = 0; j < HIDDEN; ++j) {
            float acc = hidden[j];
            acc = fmaf(he0, w0[j], acc);
            acc = fmaf(he1, w1[j], acc);
            acc = fmaf(he2, w2[j], acc);
            acc = fmaf(he3, w3[j], acc);
            hidden[j] = acc;
        }
    }

    float score = b2[0];
#pragma unroll
    for (int j = 0; j < HIDDEN; ++j) {
        float r = hidden[j] > 0.0f ? hidden[j] : 0.0f;
        score = fmaf(r, W2[j], score);
    }
    out[e] = score;
}

extern "C" void kernel_launch(void* const* d_in, const int* in_sizes, int n_in,
                              void* d_out, int out_size, void* d_ws, size_t ws_size,
                              hipStream_t stream) {
    const float* h   = (const float*)d_in[0];
    const int*   src = (const int*)  d_in[1];
    const int*   dst = (const int*)  d_in[2];
    const float* W1  = (const float*)d_in[3];
    const float* b1  = (const float*)d_in[4];
    const float* W2  = (const float*)d_in[5];
    const float* b2  = (const float*)d_in[6];
    float* out = (float*)d_out;

    int n_node_feats = in_sizes[0];            // N * 128
    int n_edges = in_sizes[1];
    int n_nodes = n_node_feats / H_FEATS;
    int nbuck = (n_nodes + (1 << BUCKET_SHIFT) - 1) >> BUCKET_SHIFT;

    const int block = 256;
    int egrid  = (n_edges + block - 1) / block;          // MLP grid (256 edges/block)
    int sgrid  = (n_edges + SORT_EPB - 1) / SORT_EPB;    // sort-pass grid

    // ws layout (256B aligned)
    size_t hh_bytes  = (size_t)n_node_feats * sizeof(__half);
    size_t off_w1t   = (hh_bytes + 255) & ~(size_t)255;
    size_t off_spair = (off_w1t + (size_t)H_FEATS * HIDDEN * 2 + 255) & ~(size_t)255;
    size_t off_seid  = off_spair + (size_t)n_edges * 8;
    size_t off_bh    = off_seid + (size_t)n_edges * 4;
    size_t off_rsum  = off_bh + (size_t)nbuck * sgrid * 4;
    size_t off_base  = off_rsum + (size_t)MAX_BUCKETS * 4;
    size_t need_full = off_base + (size_t)MAX_BUCKETS * 4;

    if (ws_size >= need_full && nbuck <= MAX_BUCKETS) {
        char* ws = (char*)d_ws;
        __half* hh     = (__half*)ws;
        __half* w1t    = (__half*)(ws + off_w1t);
        int2*   spair  = (int2*)(ws + off_spair);
        int*    seid   = (int*)(ws + off_seid);
        int*    blockhist = (int*)(ws + off_bh);
        int*    rowsum = (int*)(ws + off_rsum);
        int*    base   = (int*)(ws + off_base);

        int n8 = n_node_feats / 8;
        convert_h_kernel<<<(n8 + block - 1) / block, block, 0, stream>>>(h, hh, n8);
        convert_w_kernel<<<(H_FEATS * HIDDEN + block - 1) / block, block, 0, stream>>>(W1, w1t);
        hist_kernel<<<sgrid, block, 0, stream>>>(src, blockhist, n_edges, nbuck, sgrid);
        scan_rows_kernel<<<nbuck, block, 0, stream>>>(blockhist, rowsum, sgrid);
        scan_base_kernel<<<1, MAX_BUCKETS, 0, stream>>>(rowsum, base, nbuck);
        scatter_kernel<<<sgrid, block, 0, stream>>>(src, dst, blockhist, base,
                                                    spair, seid,
                                                    n_edges, nbuck, sgrid);
        edge_mlp_mfma_kernel<<<egrid, block, 0, stream>>>(hh, w1t, spair, seid,
                                                          b1, W2, b2, out,
                                                          n_edges, egrid);
    } else if (ws_size >= hh_bytes) {
        __half* hh = (__half*)d_ws;
        int n8 = n_node_feats / 8;
        convert_h_kernel<<<(n8 + block - 1) / block, block, 0, stream>>>(h, hh, n8);
        edge_mlp_fp16_kernel<<<egrid, block, 0, stream>>>(hh, src, dst,
                                                          W1, b1, W2, b2, out, n_edges);
    } else {
        edge_mlp_kernel<<<egrid, block, 0, stream>>>(h, src, dst,
                                                     W1, b1, W2, b2, out, n_edges);
    }
}

// Round 12
// 171.167 us; speedup vs baseline: 5.5733x; 1.0183x over previous
//
#include <hip/hip_runtime.h>
#include <hip/hip_bf16.h>
#include <hip/hip_fp16.h>

#define H_FEATS 128
#define HIDDEN  32
#define BUCKET_SHIFT 9            // 512 nodes/bucket = 256KB fp16 window
#define MAX_BUCKETS 1024
#define SORT_EPB 4096             // edges per block in sort passes

typedef _Float16 f16x8 __attribute__((ext_vector_type(8)));
typedef float    f32x4 __attribute__((ext_vector_type(4)));

union H8 { uint4 u; __half2 h2[4]; };
union U16 { uint4 u; f16x8 h; };

// ---- device helpers for prep work ----
__device__ __forceinline__ void do_convert_h(
    const float* __restrict__ h, __half* __restrict__ hh, int i, int n8)
{
    if (i >= n8) return;
    const float4* s = reinterpret_cast<const float4*>(h) + (size_t)i * 2;
    float4 a = s[0], b = s[1];
    H8 r;
    r.h2[0] = __floats2half2_rn(a.x, a.y);
    r.h2[1] = __floats2half2_rn(a.z, a.w);
    r.h2[2] = __floats2half2_rn(b.x, b.y);
    r.h2[3] = __floats2half2_rn(b.z, b.w);
    reinterpret_cast<uint4*>(hh)[i] = r.u;
}

// ---- Fused prep: convert_h | convert_w | per-block histogram ----
// Block ranges: [0, cb) convert_h; [cb, cb+wb) convert W1->W1T;
// [cb+wb, cb+wb+hb) histogram (uses LDS).
__global__ __launch_bounds__(256) void prep_fused_kernel(
    const float* __restrict__ h, __half* __restrict__ hh, int n8,
    const float* __restrict__ W1, __half* __restrict__ w1t,
    const int* __restrict__ src, int* __restrict__ blockhist,
    int n_edges, int nbuck, int hb, int cb, int wb)
{
    __shared__ int lh[MAX_BUCKETS];
    int bid = blockIdx.x;
    int tid = threadIdx.x;

    if (bid < cb) {
        do_convert_h(h, hh, bid * 256 + tid, n8);
        return;
    }
    bid -= cb;
    if (bid < wb) {
        int t = bid * 256 + tid;
        if (t < H_FEATS * HIDDEN) {
            int k = t >> 5, n = t & 31;
            w1t[(size_t)n * H_FEATS + k] = __float2half(W1[t]);
        }
        return;
    }
    bid -= wb;
    // histogram block
    for (int i = tid; i < nbuck; i += 256) lh[i] = 0;
    __syncthreads();
    int ebase = bid * SORT_EPB;
#pragma unroll
    for (int k = 0; k < SORT_EPB / 256; ++k) {
        int e = ebase + k * 256 + tid;
        if (e < n_edges) atomicAdd(&lh[src[e] >> BUCKET_SHIFT], 1);  // LDS atomic
    }
    __syncthreads();
    for (int i = tid; i < nbuck; i += 256)
        blockhist[(size_t)i * hb + bid] = lh[i];
}

// ---- standalone convert (fallback paths) ----
__global__ __launch_bounds__(256) void convert_h_kernel(
    const float* __restrict__ h, __half* __restrict__ hh, int n8)
{
    do_convert_h(h, hh, blockIdx.x * blockDim.x + threadIdx.x, n8);
}

// ---- Sort pass B1: exclusive scan each bucket-row across blocks ----
__global__ __launch_bounds__(256) void scan_rows_kernel(
    int* __restrict__ blockhist, int* __restrict__ rowsum, int nblocks)
{
    __shared__ int tmp[256];
    int row = blockIdx.x;
    int tid = threadIdx.x;
    size_t rowbase = (size_t)row * nblocks;
    int carry = 0;
    for (int c = 0; c < nblocks; c += 256) {
        int idx = c + tid;
        int v = (idx < nblocks) ? blockhist[rowbase + idx] : 0;
        tmp[tid] = v;
        __syncthreads();
#pragma unroll
        for (int d = 1; d < 256; d <<= 1) {
            int t = (tid >= d) ? tmp[tid - d] : 0;
            __syncthreads();
            tmp[tid] += t;
            __syncthreads();
        }
        int incl = tmp[tid];
        if (idx < nblocks) blockhist[rowbase + idx] = carry + incl - v;
        carry += tmp[255];
        __syncthreads();
    }
    if (tid == 0) rowsum[row] = carry;
}

// ---- Sort pass B2: exclusive scan of bucket totals -> base ----
__global__ __launch_bounds__(MAX_BUCKETS) void scan_base_kernel(
    const int* __restrict__ rowsum, int* __restrict__ base, int nbuck)
{
    __shared__ int tmp[MAX_BUCKETS];
    int tid = threadIdx.x;
    int v = (tid < nbuck) ? rowsum[tid] : 0;
    tmp[tid] = v;
    __syncthreads();
#pragma unroll
    for (int d = 1; d < MAX_BUCKETS; d <<= 1) {
        int t = (tid >= d) ? tmp[tid - d] : 0;
        __syncthreads();
        tmp[tid] += t;
        __syncthreads();
    }
    if (tid < nbuck) base[tid] = tmp[tid] - v;
}

// ---- Sort pass C: place edges via LDS cursors (no global atomics) ----
__global__ __launch_bounds__(256) void scatter_kernel(
    const int* __restrict__ src, const int* __restrict__ dst,
    const int* __restrict__ blockhist, const int* __restrict__ base,
    int2* __restrict__ spair, int* __restrict__ seid,
    int n_edges, int nbuck, int nblocks)
{
    __shared__ int lcur[MAX_BUCKETS];
    int tid = threadIdx.x;
    for (int i = tid; i < nbuck; i += 256)
        lcur[i] = base[i] + blockhist[(size_t)i * nblocks + blockIdx.x];
    __syncthreads();
    int ebase = blockIdx.x * SORT_EPB;
#pragma unroll
    for (int k = 0; k < SORT_EPB / 256; ++k) {
        int e = ebase + k * 256 + tid;
        if (e < n_edges) {
            int s = src[e];
            int p = atomicAdd(&lcur[s >> BUCKET_SHIFT], 1);   // LDS atomic
            spair[p] = make_int2(s, dst[e]);
            seid[p] = e;
        }
    }
}

// ---- MFMA MLP helpers (arrays with compile-time indices only) ----
__device__ __forceinline__ void issue_g(
    const __half* __restrict__ hh, int2 sp, int koff, U16 (&A)[4], U16 (&B)[4])
{
    const __half* hs = hh + (size_t)sp.x * H_FEATS;
    const __half* hd = hh + (size_t)sp.y * H_FEATS;
#pragma unroll
    for (int s = 0; s < 4; ++s) {
        A[s].u = *reinterpret_cast<const uint4*>(hs + s * 32 + koff);
        B[s].u = *reinterpret_cast<const uint4*>(hd + s * 32 + koff);
    }
}

__device__ __forceinline__ void compute_g(
    U16 (&A)[4], U16 (&B)[4], const f16x8 (&w1frag)[2][4],
    const float* b1lop, const float* b1hip, const float* w2lop, const float* w2hip,
    float b2f, int kq, int sid, bool eok, float* __restrict__ out)
{
    f32x4 acc0 = {0.f, 0.f, 0.f, 0.f};
    f32x4 acc1 = {0.f, 0.f, 0.f, 0.f};
#pragma unroll
    for (int s = 0; s < 4; ++s) {
        f16x8 he = A[s].h * B[s].h;
        acc0 = __builtin_amdgcn_mfma_f32_16x16x32_f16(w1frag[0][s], he, acc0, 0, 0, 0);
        acc1 = __builtin_amdgcn_mfma_f32_16x16x32_f16(w1frag[1][s], he, acc1, 0, 0, 0);
    }
    float p = 0.f;
#pragma unroll
    for (int r = 0; r < 4; ++r) {
        float h0 = acc0[r] + b1lop[r]; h0 = h0 > 0.f ? h0 : 0.f;
        float h1 = acc1[r] + b1hip[r]; h1 = h1 > 0.f ? h1 : 0.f;
        p = fmaf(h0, w2lop[r], p);
        p = fmaf(h1, w2hip[r], p);
    }
    p += __shfl_xor(p, 16, 64);
    p += __shfl_xor(p, 32, 64);
    if (kq == 0 && eok) out[sid] = p + b2f;
}

// ---- MFMA MLP over sorted edges (operand-swapped: D = W1T-tile @ he^T) ----
// 3-deep software pipeline over 4 groups of 16 edges; sched_barrier(0) pins
// stages. NOTE r6-r11: time invariant at ~127us across ILP 1->3-deep and
// occupancy 50%->31% -> kernel sits at the per-CU outstanding-miss (MSHR) x
// L3-latency floor (~25K misses/CU * ~300-600cy / ~64 MSHR ~= 100-120us).
__global__ __launch_bounds__(256, 2) void edge_mlp_mfma_kernel(
    const __half* __restrict__ hh,
    const __half* __restrict__ w1t,    // [32][128] fp16
    const int2*  __restrict__ spair,   // sorted (src,dst)
    const int*   __restrict__ seid,    // sorted -> original edge id
    const float* __restrict__ b1,
    const float* __restrict__ W2,
    const float* __restrict__ b2,
    float*       __restrict__ out,
    int n_edges, int nblocks)
{
    // Bijective XCD chunking: contiguous sorted range per XCD -> src rows L2-hit.
    int bid = blockIdx.x;
    int q8 = nblocks >> 3, r8 = nblocks & 7;
    int xcd = bid & 7, idx = bid >> 3;
    int chunk = (xcd < r8) ? (xcd * (q8 + 1) + idx)
                           : (r8 * (q8 + 1) + (xcd - r8) * q8 + idx);
    int tile = chunk * 256;

    int lane = (int)(threadIdx.x & 63);
    int wv   = (int)(threadIdx.x >> 6);
    int m    = lane & 15;
    int kq   = lane >> 4;
    int koff = kq * 8;

    // A fragments: w1frag[nt][s] = W1T rows (hidden) 16*nt+m, k = 32*s+kq*8+[0..8)
    f16x8 w1frag[2][4];
#pragma unroll
    for (int nt = 0; nt < 2; ++nt)
#pragma unroll
        for (int s = 0; s < 4; ++s) {
            U16 t;
            t.u = *reinterpret_cast<const uint4*>(
                w1t + (size_t)(nt * 16 + m) * H_FEATS + s * 32 + koff);
            w1frag[nt][s] = t.h;
        }

    // Per-lane bias/W2 slices: hidden j = kq*4+r (acc0) and 16+kq*4+r (acc1).
    float4 b1lo = *reinterpret_cast<const float4*>(b1 + kq * 4);
    float4 b1hi = *reinterpret_cast<const float4*>(b1 + 16 + kq * 4);
    float4 w2lo = *reinterpret_cast<const float4*>(W2 + kq * 4);
    float4 w2hi = *reinterpret_cast<const float4*>(W2 + 16 + kq * 4);
    const float* b1lop = reinterpret_cast<const float*>(&b1lo);
    const float* b1hip = reinterpret_cast<const float*>(&b1hi);
    const float* w2lop = reinterpret_cast<const float*>(&w2lo);
    const float* w2hip = reinterpret_cast<const float*>(&w2hi);
    float b2f = b2[0];

    int base = tile + wv * 64;

    // Preload edge metadata for all 4 groups.
    int e0 = base + m,      e1 = base + 16 + m;
    int e2 = base + 32 + m, e3 = base + 48 + m;
    bool ok0 = e0 < n_edges, ok1 = e1 < n_edges, ok2 = e2 < n_edges, ok3 = e3 < n_edges;
    int2 sp0 = spair[ok0 ? e0 : n_edges - 1];
    int2 sp1 = spair[ok1 ? e1 : n_edges - 1];
    int2 sp2 = spair[ok2 ? e2 : n_edges - 1];
    int2 sp3 = spair[ok3 ? e3 : n_edges - 1];
    int sid0 = seid[ok0 ? e0 : n_edges - 1];
    int sid1 = seid[ok1 ? e1 : n_edges - 1];
    int sid2 = seid[ok2 ? e2 : n_edges - 1];
    int sid3 = seid[ok3 ? e3 : n_edges - 1];

    // Three named buffer sets (24 uint4 = 96 VGPRs of gather data in flight).
    U16 xA[4], xB[4];
    U16 yA[4], yB[4];
    U16 zA[4], zB[4];

    issue_g(hh, sp0, koff, xA, xB);
    issue_g(hh, sp1, koff, yA, yB);
    issue_g(hh, sp2, koff, zA, zB);
    __builtin_amdgcn_sched_barrier(0);
    compute_g(xA, xB, w1frag, b1lop, b1hip, w2lop, w2hip, b2f, kq, sid0, ok0, out);
    __builtin_amdgcn_sched_barrier(0);
    issue_g(hh, sp3, koff, xA, xB);
    __builtin_amdgcn_sched_barrier(0);
    compute_g(yA, yB, w1frag, b1lop, b1hip, w2lop, w2hip, b2f, kq, sid1, ok1, out);
    __builtin_amdgcn_sched_barrier(0);
    compute_g(zA, zB, w1frag, b1lop, b1hip, w2lop, w2hip, b2f, kq, sid2, ok2, out);
    __builtin_amdgcn_sched_barrier(0);
    compute_g(xA, xB, w1frag, b1lop, b1hip, w2lop, w2hip, b2f, kq, sid3, ok3, out);
}

// ---- Fallback: unsorted fp16 scalar path ----
__global__ __launch_bounds__(256) void edge_mlp_fp16_kernel(
    const __half* __restrict__ hh,
    const int*   __restrict__ src,
    const int*   __restrict__ dst,
    const float* __restrict__ W1,
    const float* __restrict__ b1,
    const float* __restrict__ W2,
    const float* __restrict__ b2,
    float*       __restrict__ out,
    int n_edges)
{
    int e = blockIdx.x * blockDim.x + threadIdx.x;
    if (e >= n_edges) return;

    const __half* hs = hh + (size_t)src[e] * H_FEATS;
    const __half* hd = hh + (size_t)dst[e] * H_FEATS;

    float hidden[HIDDEN];
#pragma unroll
    for (int j = 0; j < HIDDEN; ++j) hidden[j] = b1[j];

#pragma unroll 2
    for (int f0 = 0; f0 < H_FEATS; f0 += 8) {
        H8 A, B;
        A.u = *reinterpret_cast<const uint4*>(hs + f0);
        B.u = *reinterpret_cast<const uint4*>(hd + f0);
        float he[8];
#pragma unroll
        for (int k = 0; k < 4; ++k) {
            float2 a = __half22float2(A.h2[k]);
            float2 b = __half22float2(B.h2[k]);
            he[2 * k]     = a.x * b.x;
            he[2 * k + 1] = a.y * b.y;
        }
        const float* w = W1 + (size_t)f0 * HIDDEN;
#pragma unroll
        for (int j = 0; j < HIDDEN; ++j) {
            float acc = hidden[j];
#pragma unroll
            for (int k = 0; k < 8; ++k)
                acc = fmaf(he[k], w[(size_t)k * HIDDEN + j], acc);
            hidden[j] = acc;
        }
    }

    float score = b2[0];
#pragma unroll
    for (int j = 0; j < HIDDEN; ++j) {
        float r = hidden[j] > 0.0f ? hidden[j] : 0.0f;
        score = fmaf(r, W2[j], score);
    }
    out[e] = score;
}

// ---- Fallback: fp32 path (tiny ws) ----
__global__ __launch_bounds__(256) void edge_mlp_kernel(
    const float* __restrict__ h,
    const int*   __restrict__ src,
    const int*   __restrict__ dst,
    const float* __restrict__ W1,
    const float* __restrict__ b1,
    const float* __restrict__ W2,
    const float* __restrict__ b2,
    float*       __restrict__ out,
    int n_edges)
{
    int e = blockIdx.x * blockDim.x + threadIdx.x;
    if (e >= n_edges) return;

    const float* hs = h + (size_t)src[e] * H_FEATS;
    const float* hd = h + (size_t)dst[e] * H_FEATS;

    float hidden[HIDDEN];
#pragma unroll
    for (int j = 0; j < HIDDEN; ++j) hidden[j] = b1[j];

#pragma unroll 4
    for (int f0 = 0; f0 < H_FEATS; f0 += 4) {
        float4 a = *reinterpret_cast<const float4*>(hs + f0);
        float4 b = *reinterpret_cast<const float4*>(hd + f0);
        float he0 = a.x * b.x, he1 = a.y * b.y, he2 = a.z * b.z, he3 = a.w * b.w;
        const float* w0 = W1 + (size_t)(f0 + 0) * HIDDEN;
        const float* w1 = W1 + (size_t)(f0 + 1) * HIDDEN;
        const float* w2 = W1 + (size_t)(f0 + 2) * HIDDEN;
        const float* w3 = W1 + (size_t)(f0 + 3) * HIDDEN;
#pragma unroll
        for (int j = 0; j < HIDDEN; ++j) {
            float acc = hidden[j];
            acc = fmaf(he0, w0[j], acc);
            acc = fmaf(he1, w1[j], acc);
            acc = fmaf(he2, w2[j], acc);
            acc = fmaf(he3, w3[j], acc);
            hidden[j] = acc;
        }
    }

    float score = b2[0];
#pragma unroll
    for (int j = 0; j < HIDDEN; ++j) {
        float r = hidden[j] > 0.0f ? hidden[j] : 0.0f;
        score = fmaf(r, W2[j], score);
    }
    out[e] = score;
}

extern "C" void kernel_launch(void* const* d_in, const int* in_sizes, int n_in,
                              void* d_out, int out_size, void* d_ws, size_t ws_size,
                              hipStream_t stream) {
    const float* h   = (const float*)d_in[0];
    const int*   src = (const int*)  d_in[1];
    const int*   dst = (const int*)  d_in[2];
    const float* W1  = (const float*)d_in[3];
    const float* b1  = (const float*)d_in[4];
    const float* W2  = (const float*)d_in[5];
    const float* b2  = (const float*)d_in[6];
    float* out = (float*)d_out;

    int n_node_feats = in_sizes[0];            // N * 128
    int n_edges = in_sizes[1];
    int n_nodes = n_node_feats / H_FEATS;
    int nbuck = (n_nodes + (1 << BUCKET_SHIFT) - 1) >> BUCKET_SHIFT;

    const int block = 256;
    int egrid  = (n_edges + block - 1) / block;          // MLP grid (256 edges/block)
    int sgrid  = (n_edges + SORT_EPB - 1) / SORT_EPB;    // sort-pass grid

    // ws layout (256B aligned)
    size_t hh_bytes  = (size_t)n_node_feats * sizeof(__half);
    size_t off_w1t   = (hh_bytes + 255) & ~(size_t)255;
    size_t off_spair = (off_w1t + (size_t)H_FEATS * HIDDEN * 2 + 255) & ~(size_t)255;
    size_t off_seid  = off_spair + (size_t)n_edges * 8;
    size_t off_bh    = off_seid + (size_t)n_edges * 4;
    size_t off_rsum  = off_bh + (size_t)nbuck * sgrid * 4;
    size_t off_base  = off_rsum + (size_t)MAX_BUCKETS * 4;
    size_t need_full = off_base + (size_t)MAX_BUCKETS * 4;

    int n8 = n_node_feats / 8;

    if (ws_size >= need_full && nbuck <= MAX_BUCKETS) {
        char* ws = (char*)d_ws;
        __half* hh     = (__half*)ws;
        __half* w1t    = (__half*)(ws + off_w1t);
        int2*   spair  = (int2*)(ws + off_spair);
        int*    seid   = (int*)(ws + off_seid);
        int*    blockhist = (int*)(ws + off_bh);
        int*    rowsum = (int*)(ws + off_rsum);
        int*    base   = (int*)(ws + off_base);

        int cb = (n8 + block - 1) / block;
        int wb = (H_FEATS * HIDDEN + block - 1) / block;
        int hb = sgrid;
        prep_fused_kernel<<<cb + wb + hb, block, 0, stream>>>(
            h, hh, n8, W1, w1t, src, blockhist, n_edges, nbuck, hb, cb, wb);
        scan_rows_kernel<<<nbuck, block, 0, stream>>>(blockhist, rowsum, sgrid);
        scan_base_kernel<<<1, MAX_BUCKETS, 0, stream>>>(rowsum, base, nbuck);
        scatter_kernel<<<sgrid, block, 0, stream>>>(src, dst, blockhist, base,
                                                    spair, seid,
                                                    n_edges, nbuck, sgrid);
        edge_mlp_mfma_kernel<<<egrid, block, 0, stream>>>(hh, w1t, spair, seid,
                                                          b1, W2, b2, out,
                                                          n_edges, egrid);
    } else if (ws_size >= hh_bytes) {
        __half* hh = (__half*)d_ws;
        convert_h_kernel<<<(n8 + block - 1) / block, block, 0, stream>>>(h, hh, n8);
        edge_mlp_fp16_kernel<<<egrid, block, 0, stream>>>(hh, src, dst,
                                                          W1, b1, W2, b2, out, n_edges);
    } else {
        edge_mlp_kernel<<<egrid, block, 0, stream>>>(h, src, dst,
                                                     W1, b1, W2, b2, out, n_edges);
    }
}